// Round 4
// baseline (454.849 us; speedup 1.0000x reference)
//
#include <hip/hip_runtime.h>
#include <math.h>

#define SCALE_ 0.125f

typedef __attribute__((ext_vector_type(8))) short bf16x8;
typedef __attribute__((ext_vector_type(4))) short bf16x4;
typedef __attribute__((ext_vector_type(4))) float f32x4;

__device__ inline short f2bf(float f) {
  unsigned u = __builtin_bit_cast(unsigned, f);
  u += 0x7fff + ((u >> 16) & 1);
  return (short)(u >> 16);
}

// ---------- transpose x [B,D,M,N] -> xt [B,N,M,D] fp32 + bf16 ----------
__global__ __launch_bounds__(256) void k_transpose(const float* __restrict__ x, float* __restrict__ xt,
                                                   short* __restrict__ xtbf) {
  __shared__ float tile[32][33];
  int bm = blockIdx.z; int b = bm >> 3; int m = bm & 7;
  int d0 = blockIdx.x * 32, n0 = blockIdx.y * 32;
#pragma unroll
  for (int r = 0; r < 32; r += 8) {
    int d = d0 + threadIdx.y + r, n = n0 + threadIdx.x;
    tile[threadIdx.y + r][threadIdx.x] = x[((size_t)(b * 256 + d) * 8 + m) * 256 + n];
  }
  __syncthreads();
#pragma unroll
  for (int r = 0; r < 32; r += 8) {
    int n = n0 + threadIdx.y + r, d = d0 + threadIdx.x;
    float v = tile[threadIdx.x][threadIdx.y + r];
    size_t idx = ((size_t)(b * 256 + n) * 8 + m) * 256 + d;
    xt[idx] = v;
    xtbf[idx] = f2bf(v);
  }
}

// ---------- weight transpose+convert: W fp32 [K][N] -> WT bf16 [N][K] ----------
__global__ __launch_bounds__(256) void k_wt(const float* __restrict__ W, short* __restrict__ WT, int K, int N) {
  __shared__ float tile[32][33];
  int n0 = blockIdx.x * 32, k0 = blockIdx.y * 32;
  int tx = threadIdx.x & 31, ty = threadIdx.x >> 5;
#pragma unroll
  for (int r = 0; r < 32; r += 8)
    tile[ty + r][tx] = W[(size_t)(k0 + ty + r) * N + n0 + tx];
  __syncthreads();
#pragma unroll
  for (int r = 0; r < 32; r += 8)
    WT[(size_t)(n0 + ty + r) * K + k0 + tx] = f2bf(tile[tx][ty + r]);
}

// ---------- bf16 MFMA GEMM: C[M,N] = A[M,K](bf16) @ BT[N,K](bf16) + bias ----------
__global__ __launch_bounds__(256) void k_gemm_bf(const short* __restrict__ A, const short* __restrict__ Bt,
                                                 const float* __restrict__ bias, float* __restrict__ C,
                                                 int M, int N, int K) {
  __shared__ short As[64 * 40];
  __shared__ short Bs[64 * 40];
  int t = threadIdx.x;
  int row0 = blockIdx.y * 64, col0 = blockIdx.x * 64;
  int w = t >> 6, lane = t & 63, quad = lane >> 4, l16 = lane & 15;
  int wr = w >> 1, wc = w & 1;
  int lrow = t >> 2, lch = (t & 3) * 8;
  f32x4 acc[2][2] = {{{0,0,0,0},{0,0,0,0}},{{0,0,0,0},{0,0,0,0}}};
  for (int k0 = 0; k0 < K; k0 += 32) {
    bf16x8 av = *(const bf16x8*)(A + (size_t)(row0 + lrow) * K + k0 + lch);
    bf16x8 bv = *(const bf16x8*)(Bt + (size_t)(col0 + lrow) * K + k0 + lch);
    *(bf16x8*)&As[lrow * 40 + lch] = av;
    *(bf16x8*)&Bs[lrow * 40 + lch] = bv;
    __syncthreads();
    bf16x8 af[2], bf[2];
#pragma unroll
    for (int rf = 0; rf < 2; rf++) af[rf] = *(const bf16x8*)&As[(wr * 32 + rf * 16 + l16) * 40 + quad * 8];
#pragma unroll
    for (int cf = 0; cf < 2; cf++) bf[cf] = *(const bf16x8*)&Bs[(wc * 32 + cf * 16 + l16) * 40 + quad * 8];
#pragma unroll
    for (int rf = 0; rf < 2; rf++)
#pragma unroll
      for (int cf = 0; cf < 2; cf++)
        acc[rf][cf] = __builtin_amdgcn_mfma_f32_16x16x32_bf16(af[rf], bf[cf], acc[rf][cf], 0, 0, 0);
    __syncthreads();
  }
#pragma unroll
  for (int rf = 0; rf < 2; rf++)
#pragma unroll
    for (int cf = 0; cf < 2; cf++) {
      int col = col0 + wc * 32 + cf * 16 + l16;
      float vb = bias ? bias[col] : 0.0f;
#pragma unroll
      for (int r = 0; r < 4; r++) {
        int row = row0 + wr * 32 + rf * 16 + quad * 4 + r;
        C[(size_t)row * N + col] = acc[rf][cf][r] + vb;
      }
    }
}

// ---------- prep: q fp32 [4096,512] -> qbf2[bh][m*256+i][d] bf16 ----------
__global__ __launch_bounds__(256) void k_prep_q(const float* __restrict__ q, short* __restrict__ qbf) {
  int c = blockIdx.x * 256 + threadIdx.x;
  int dc = c & 7, h = (c >> 3) & 7, row = c >> 6;
  int b = row >> 11;
  int m = row & 7, i = (row >> 3) & 255;
  const float* src = q + (size_t)row * 512 + h * 64 + dc * 8;
  float4 f0 = *(const float4*)src, f1 = *(const float4*)(src + 4);
  bf16x8 o;
  o[0] = f2bf(f0.x); o[1] = f2bf(f0.y); o[2] = f2bf(f0.z); o[3] = f2bf(f0.w);
  o[4] = f2bf(f1.x); o[5] = f2bf(f1.y); o[6] = f2bf(f1.z); o[7] = f2bf(f1.w);
  *(bf16x8*)(qbf + (size_t)((b * 8 + h) * 2048 + m * 256 + i) * 64 + dc * 8) = o;
}

// ---------- prep: kv k-part -> kbf2[bh][z*256+j][d] bf16 ----------
__global__ __launch_bounds__(256) void k_prep_k(const float* __restrict__ kv, short* __restrict__ kbf) {
  int c = blockIdx.x * 256 + threadIdx.x;
  int dc = c & 7, h = (c >> 3) & 7, row = c >> 6;
  int b = row >> 11;
  int z = row & 7, j = (row >> 3) & 255;
  const float* src = kv + (size_t)row * 1024 + h * 64 + dc * 8;
  float4 f0 = *(const float4*)src, f1 = *(const float4*)(src + 4);
  bf16x8 o;
  o[0] = f2bf(f0.x); o[1] = f2bf(f0.y); o[2] = f2bf(f0.z); o[3] = f2bf(f0.w);
  o[4] = f2bf(f1.x); o[5] = f2bf(f1.y); o[6] = f2bf(f1.z); o[7] = f2bf(f1.w);
  *(bf16x8*)(kbf + (size_t)((b * 8 + h) * 2048 + z * 256 + j) * 64 + dc * 8) = o;
}

// ---------- prep: kv v-part -> vT[bh][d][m*256+j] bf16 (transposed) ----------
__global__ __launch_bounds__(256) void k_prep_v(const float* __restrict__ kv, short* __restrict__ vT) {
  __shared__ float ld[64][68];
  int jt = blockIdx.x, m = blockIdx.y, bh = blockIdx.z;
  int b = bh >> 3, h = bh & 7;
  int t = threadIdx.x;
  int jr = t >> 2, c4 = t & 3;
  const float* src = kv + (size_t)((b * 256 + jt * 64 + jr) * 8 + m) * 1024 + 512 + h * 64;
#pragma unroll
  for (int r = 0; r < 4; r++) {
    float4 f = *(const float4*)(src + (c4 + r * 4) * 4);
    *(float4*)&ld[jr][(c4 + r * 4) * 4] = f;
  }
  __syncthreads();
  int d = t >> 2, jg = (t & 3) * 16;
  short* dst = vT + (size_t)(bh * 64 + d) * 2048 + m * 256 + jt * 64 + jg;
  bf16x8 o0, o1;
#pragma unroll
  for (int jj = 0; jj < 8; jj++) o0[jj] = f2bf(ld[jg + jj][d]);
#pragma unroll
  for (int jj = 0; jj < 8; jj++) o1[jj] = f2bf(ld[jg + 8 + jj][d]);
  *(bf16x8*)dst = o0;
  *(bf16x8*)(dst + 8) = o1;
}

// ---------- attention pass 1: rdg2[bh][m][zj] = 1/sum_i exp(S'[(m,i)][zj]*scale) ----------
// grid (ct 32, bh 16); block 256; wave w owns 16 cols
__global__ __launch_bounds__(256) void k_attn_den2(const short* __restrict__ qbf, const short* __restrict__ kbf,
                                                   float* __restrict__ rdg) {
  int ct = blockIdx.x, bh = blockIdx.y;
  int t = threadIdx.x;
  int w = t >> 6, lane = t & 63, quad = lane >> 4, l16 = lane & 15;
  const short* qb = qbf + (size_t)bh * 131072;
  const short* kb = kbf + (size_t)bh * 131072;
  int col = ct * 64 + w * 16 + l16;
  bf16x8 bfr[2];
#pragma unroll
  for (int ks = 0; ks < 2; ks++)
    bfr[ks] = *(const bf16x8*)(kb + (size_t)col * 64 + ks * 32 + quad * 8);
  for (int mg = 0; mg < 8; mg++) {
    float facc = 0.0f;
#pragma unroll 2
    for (int rs = 0; rs < 16; rs++) {
      const short* ap = qb + (size_t)(mg * 256 + rs * 16 + l16) * 64 + quad * 8;
      bf16x8 a0 = *(const bf16x8*)ap;
      bf16x8 a1 = *(const bf16x8*)(ap + 32);
      f32x4 c = {0, 0, 0, 0};
      c = __builtin_amdgcn_mfma_f32_16x16x32_bf16(a0, bfr[0], c, 0, 0, 0);
      c = __builtin_amdgcn_mfma_f32_16x16x32_bf16(a1, bfr[1], c, 0, 0, 0);
#pragma unroll
      for (int r = 0; r < 4; r++) facc += __expf(c[r] * SCALE_);
    }
    facc += __shfl_xor(facc, 16);
    facc += __shfl_xor(facc, 32);
    if (lane < 16)
      rdg[(size_t)(bh * 8 + mg) * 2048 + col] = 1.0f / facc;
  }
}

// ---------- attention pass 2: out^T_z[d][i] via S'^T register-direct PV ----------
// grid (zp 4, it 16, bh 16); block 256 (4 waves, wave = m-pair {2w,2w+1})
__global__ __launch_bounds__(256) void k_attn_out2(const short* __restrict__ qbf, const short* __restrict__ kbf,
                                                   const short* __restrict__ vT, const float* __restrict__ rdg,
                                                   short* __restrict__ ao) {
  __shared__ float red[4 * 64 * 17];
  int zp = blockIdx.x, it = blockIdx.y, bh = blockIdx.z;
  int b = bh >> 3, h = bh & 7;
  int i0 = it * 16;
  int t = threadIdx.x, w = t >> 6, lane = t & 63, quad = lane >> 4, l16 = lane & 15;
  const short* qb = qbf + (size_t)bh * 131072;
  const short* kb = kbf + (size_t)bh * 131072;
  const short* vb = vT + (size_t)bh * 131072;
  const float* rb = rdg + (size_t)bh * 16384;
  int m0 = 2 * w;
  // Q B-frags: constant per block
  bf16x8 qf[2][2];
#pragma unroll
  for (int mm = 0; mm < 2; mm++)
#pragma unroll
    for (int ks = 0; ks < 2; ks++)
      qf[mm][ks] = *(const bf16x8*)(qb + (size_t)((m0 + mm) * 256 + i0 + l16) * 64 + ks * 32 + quad * 8);
  for (int z2 = 0; z2 < 2; z2++) {
    int z = zp * 2 + z2;
    f32x4 acc[4] = {{0,0,0,0},{0,0,0,0},{0,0,0,0},{0,0,0,0}};
    for (int jc = 0; jc < 8; jc++) {
      int j0 = jc * 32;
      // QK: S'^T chunk rows (z, j0..j0+31), cols (m-pair, i0..i0+15)
      f32x4 c[2][2] = {{{0,0,0,0},{0,0,0,0}},{{0,0,0,0},{0,0,0,0}}};
#pragma unroll
      for (int jf = 0; jf < 2; jf++) {
        const short* kp = kb + (size_t)(z * 256 + j0 + jf * 16 + l16) * 64 + quad * 8;
        bf16x8 k0 = *(const bf16x8*)kp;
        bf16x8 k1 = *(const bf16x8*)(kp + 32);
#pragma unroll
        for (int mm = 0; mm < 2; mm++) {
          c[jf][mm] = __builtin_amdgcn_mfma_f32_16x16x32_bf16(k0, qf[mm][0], c[jf][mm], 0, 0, 0);
          c[jf][mm] = __builtin_amdgcn_mfma_f32_16x16x32_bf16(k1, qf[mm][1], c[jf][mm], 0, 0, 0);
        }
      }
      // P frags: exp * rden, packed so B k = quad*8+e <-> (m = e>=4, j = quad*4 + (e&3))
      bf16x8 pf[2];
#pragma unroll
      for (int jf = 0; jf < 2; jf++) {
        float4 rv0 = *(const float4*)(rb + (size_t)m0 * 2048 + z * 256 + j0 + jf * 16 + quad * 4);
        float4 rv1 = *(const float4*)(rb + (size_t)(m0 + 1) * 2048 + z * 256 + j0 + jf * 16 + quad * 4);
        float r0a[4] = {rv0.x, rv0.y, rv0.z, rv0.w};
        float r1a[4] = {rv1.x, rv1.y, rv1.z, rv1.w};
#pragma unroll
        for (int e = 0; e < 4; e++) {
          pf[jf][e]     = f2bf(__expf(c[jf][0][e] * SCALE_) * r0a[e]);
          pf[jf][e + 4] = f2bf(__expf(c[jf][1][e] * SCALE_) * r1a[e]);
        }
      }
      // PV: acc[df] += V-frag * P-frag
#pragma unroll
      for (int df = 0; df < 4; df++) {
        const short* vp = vb + (size_t)(df * 16 + l16) * 2048 + m0 * 256 + j0;
#pragma unroll
        for (int jf = 0; jf < 2; jf++) {
          bf16x4 v0 = *(const bf16x4*)(vp + jf * 16 + quad * 4);
          bf16x4 v1 = *(const bf16x4*)(vp + 256 + jf * 16 + quad * 4);
          bf16x8 vf;
          vf[0] = v0[0]; vf[1] = v0[1]; vf[2] = v0[2]; vf[3] = v0[3];
          vf[4] = v1[0]; vf[5] = v1[1]; vf[6] = v1[2]; vf[7] = v1[3];
          acc[df] = __builtin_amdgcn_mfma_f32_16x16x32_bf16(vf, pf[jf], acc[df], 0, 0, 0);
        }
      }
    }
    // cross-wave reduction over m-pairs
#pragma unroll
    for (int df = 0; df < 4; df++)
#pragma unroll
      for (int r = 0; r < 4; r++)
        red[w * 1088 + (df * 16 + quad * 4 + r) * 17 + l16] = acc[df][r];
    __syncthreads();
    {
      int i = t >> 4, dg = t & 15;
      float s[4] = {0, 0, 0, 0};
#pragma unroll
      for (int w2 = 0; w2 < 4; w2++)
#pragma unroll
        for (int r2 = 0; r2 < 4; r2++)
          s[r2] += red[w2 * 1088 + (dg * 4 + r2) * 17 + i];
      bf16x4 ov;
#pragma unroll
      for (int r2 = 0; r2 < 4; r2++) ov[r2] = f2bf(s[r2]);
      *(bf16x4*)(ao + (size_t)((b * 256 + i0 + i) * 8 + z) * 512 + h * 64 + dg * 4) = ov;
    }
    __syncthreads();
  }
}

// ---------- fused residual + layernorm; optional bf16 copy ----------
__global__ __launch_bounds__(256) void k_ln(const float* __restrict__ X, const float* __restrict__ R,
                                            const float* __restrict__ g, const float* __restrict__ be,
                                            float* __restrict__ Y, short* __restrict__ Ybf) {
  __shared__ float sm[8];
  int row = blockIdx.x, t = threadIdx.x;
  int lane = t & 63, w = t >> 6;
  size_t base = (size_t)row * 256;
  float v = X[base + t] + R[base + t];
  float s = v;
  s += __shfl_xor(s, 1); s += __shfl_xor(s, 2); s += __shfl_xor(s, 4);
  s += __shfl_xor(s, 8); s += __shfl_xor(s, 16); s += __shfl_xor(s, 32);
  if (lane == 0) sm[w] = s;
  __syncthreads();
  float mu = (sm[0] + sm[1] + sm[2] + sm[3]) * (1.0f / 256.0f);
  float dv = v - mu;
  float s2 = dv * dv;
  s2 += __shfl_xor(s2, 1); s2 += __shfl_xor(s2, 2); s2 += __shfl_xor(s2, 4);
  s2 += __shfl_xor(s2, 8); s2 += __shfl_xor(s2, 16); s2 += __shfl_xor(s2, 32);
  if (lane == 0) sm[4 + w] = s2;
  __syncthreads();
  float var = (sm[4] + sm[5] + sm[6] + sm[7]) * (1.0f / 256.0f);
  float rs = rsqrtf(var + 1e-5f);
  float res = dv * rs * g[t] + be[t];
  Y[base + t] = res;
  if (Ybf) Ybf[base + t] = f2bf(res);
}

// ---------- GEGLU -> bf16 ----------
__global__ __launch_bounds__(256) void k_geglu(const float* __restrict__ hg, short* __restrict__ gg) {
  int idx = blockIdx.x * 256 + threadIdx.x;
  int r = idx >> 10, c = idx & 1023;
  float a = hg[(size_t)r * 2048 + c];
  float gt = hg[(size_t)r * 2048 + 1024 + c];
  float ge = 0.5f * gt * (1.0f + erff(gt * 0.70710678118654752f));
  gg[idx] = f2bf(a * ge);
}

extern "C" void kernel_launch(void* const* d_in, const int* in_sizes, int n_in,
                              void* d_out, int out_size, void* d_ws, size_t ws_size,
                              hipStream_t stream) {
  const float* x    = (const float*)d_in[0];
  const float* Wq   = (const float*)d_in[1];
  const float* Wkv  = (const float*)d_in[2];
  const float* Wout = (const float*)d_in[3];
  const float* bout = (const float*)d_in[4];
  const float* g1   = (const float*)d_in[5];
  const float* be1  = (const float*)d_in[6];
  const float* Wff1 = (const float*)d_in[7];
  const float* bff1 = (const float*)d_in[8];
  const float* Wff2 = (const float*)d_in[9];
  const float* bff2 = (const float*)d_in[10];
  const float* g2   = (const float*)d_in[11];
  const float* be2  = (const float*)d_in[12];
  float* out = (float*)d_out;
  float* w = (float*)d_ws;

  // fp32 zone
  float* xt  = w;              // 1,048,576
  float* q   = w + 1048576;    // 2,097,152
  float* kv  = w + 3145728;    // 4,194,304
  float* hg  = w + 1048576;    // 8,388,608 (aliases q..kv+, dead before ff1)
  float* y   = w + 9437184;    // 1,048,576
  float* o   = w + 10485760;   // 1,048,576 (reused as ff)
  float* ff  = w + 10485760;
  float* rdg = w + 11534336;   //   262,144  [bh][m][zj]
  // bf16 zone
  short* sb     = (short*)(w + 11796480);
  short* qbf    = sb;                    // 2,097,152  [bh][m*256+i][d]
  short* kbf    = sb + 2097152;          // 2,097,152  [bh][z*256+j][d]
  short* vTb    = sb + 4194304;          // 2,097,152  [bh][d][m*256+j]
  short* xt_bf  = sb + 6291456;          // 1,048,576
  short* ao_bf  = sb + 7340032;          // 2,097,152
  short* y_bf   = sb + 9437184;          // 1,048,576
  short* gg_bf  = sb + 10485760;         // 4,194,304
  short* WqT    = sb + 14680064;
  short* WkvT   = sb + 14811136;
  short* WoutT  = sb + 15073280;
  short* Wff1T  = sb + 23461888;
  short* Wff2T  = sb + 23986176;

  k_transpose<<<dim3(8, 8, 16), dim3(32, 8), 0, stream>>>(x, xt, xt_bf);
  k_wt<<<dim3(16, 8), 256, 0, stream>>>(Wq, WqT, 256, 512);
  k_wt<<<dim3(32, 8), 256, 0, stream>>>(Wkv, WkvT, 256, 1024);
  k_wt<<<dim3(64, 128), 256, 0, stream>>>(Wout, WoutT, 4096, 2048);
  k_wt<<<dim3(64, 8), 256, 0, stream>>>(Wff1, Wff1T, 256, 2048);
  k_wt<<<dim3(8, 32), 256, 0, stream>>>(Wff2, Wff2T, 1024, 256);
  k_gemm_bf<<<dim3(8, 64), 256, 0, stream>>>(xt_bf, WqT, nullptr, q, 4096, 512, 256);
  k_gemm_bf<<<dim3(16, 64), 256, 0, stream>>>(xt_bf, WkvT, nullptr, kv, 4096, 1024, 256);
  k_prep_q<<<1024, 256, 0, stream>>>(q, qbf);
  k_prep_k<<<1024, 256, 0, stream>>>(kv, kbf);
  k_prep_v<<<dim3(4, 8, 16), 256, 0, stream>>>(kv, vTb);
  k_attn_den2<<<dim3(32, 16), 256, 0, stream>>>(qbf, kbf, rdg);
  k_attn_out2<<<dim3(4, 16, 16), 256, 0, stream>>>(qbf, kbf, vTb, rdg, ao_bf);
  k_gemm_bf<<<dim3(32, 8), 256, 0, stream>>>(ao_bf, WoutT, bout, o, 512, 2048, 4096);
  k_ln<<<4096, 256, 0, stream>>>(xt, o, g1, be1, y, y_bf);
  k_gemm_bf<<<dim3(32, 64), 256, 0, stream>>>(y_bf, Wff1T, bff1, hg, 4096, 2048, 256);
  k_geglu<<<16384, 256, 0, stream>>>(hg, gg_bf);
  k_gemm_bf<<<dim3(4, 64), 256, 0, stream>>>(gg_bf, Wff2T, bff2, ff, 4096, 256, 1024);
  k_ln<<<4096, 256, 0, stream>>>(y, ff, g2, be2, out, nullptr);
}

// Round 5
// 314.212 us; speedup vs baseline: 1.4476x; 1.4476x over previous
//
#include <hip/hip_runtime.h>
#include <math.h>

#define SCALE_ 0.125f

typedef __attribute__((ext_vector_type(8))) short bf16x8;
typedef __attribute__((ext_vector_type(4))) short bf16x4;
typedef __attribute__((ext_vector_type(4))) float f32x4;

__device__ inline short f2bf(float f) {
  unsigned u = __builtin_bit_cast(unsigned, f);
  u += 0x7fff + ((u >> 16) & 1);
  return (short)(u >> 16);
}

// ---------- transpose x [B,D,M,N] -> xt [B,N,M,D] fp32 + bf16 ----------
__global__ __launch_bounds__(256) void k_transpose(const float* __restrict__ x, float* __restrict__ xt,
                                                   short* __restrict__ xtbf) {
  __shared__ float tile[32][33];
  int bm = blockIdx.z; int b = bm >> 3; int m = bm & 7;
  int d0 = blockIdx.x * 32, n0 = blockIdx.y * 32;
#pragma unroll
  for (int r = 0; r < 32; r += 8) {
    int d = d0 + threadIdx.y + r, n = n0 + threadIdx.x;
    tile[threadIdx.y + r][threadIdx.x] = x[((size_t)(b * 256 + d) * 8 + m) * 256 + n];
  }
  __syncthreads();
#pragma unroll
  for (int r = 0; r < 32; r += 8) {
    int n = n0 + threadIdx.y + r, d = d0 + threadIdx.x;
    float v = tile[threadIdx.x][threadIdx.y + r];
    size_t idx = ((size_t)(b * 256 + n) * 8 + m) * 256 + d;
    xt[idx] = v;
    xtbf[idx] = f2bf(v);
  }
}

// ---------- weight transpose+convert: W fp32 [K][N] -> WT bf16 [N][K] ----------
__global__ __launch_bounds__(256) void k_wt(const float* __restrict__ W, short* __restrict__ WT, int K, int N) {
  __shared__ float tile[32][33];
  int n0 = blockIdx.x * 32, k0 = blockIdx.y * 32;
  int tx = threadIdx.x & 31, ty = threadIdx.x >> 5;
#pragma unroll
  for (int r = 0; r < 32; r += 8)
    tile[ty + r][tx] = W[(size_t)(k0 + ty + r) * N + n0 + tx];
  __syncthreads();
#pragma unroll
  for (int r = 0; r < 32; r += 8)
    WT[(size_t)(n0 + ty + r) * K + k0 + tx] = f2bf(tile[tx][ty + r]);
}

// ---------- bf16 MFMA GEMM: C[M,N] = A[M,K](bf16) @ BT[N,K](bf16) + bias ----------
__global__ __launch_bounds__(256) void k_gemm_bf(const short* __restrict__ A, const short* __restrict__ Bt,
                                                 const float* __restrict__ bias, float* __restrict__ C,
                                                 int M, int N, int K) {
  __shared__ short As[64 * 40];
  __shared__ short Bs[64 * 40];
  int t = threadIdx.x;
  int row0 = blockIdx.y * 64, col0 = blockIdx.x * 64;
  int w = t >> 6, lane = t & 63, quad = lane >> 4, l16 = lane & 15;
  int wr = w >> 1, wc = w & 1;
  int lrow = t >> 2, lch = (t & 3) * 8;
  f32x4 acc[2][2] = {{{0,0,0,0},{0,0,0,0}},{{0,0,0,0},{0,0,0,0}}};
  for (int k0 = 0; k0 < K; k0 += 32) {
    bf16x8 av = *(const bf16x8*)(A + (size_t)(row0 + lrow) * K + k0 + lch);
    bf16x8 bv = *(const bf16x8*)(Bt + (size_t)(col0 + lrow) * K + k0 + lch);
    *(bf16x8*)&As[lrow * 40 + lch] = av;
    *(bf16x8*)&Bs[lrow * 40 + lch] = bv;
    __syncthreads();
    bf16x8 af[2], bf[2];
#pragma unroll
    for (int rf = 0; rf < 2; rf++) af[rf] = *(const bf16x8*)&As[(wr * 32 + rf * 16 + l16) * 40 + quad * 8];
#pragma unroll
    for (int cf = 0; cf < 2; cf++) bf[cf] = *(const bf16x8*)&Bs[(wc * 32 + cf * 16 + l16) * 40 + quad * 8];
#pragma unroll
    for (int rf = 0; rf < 2; rf++)
#pragma unroll
      for (int cf = 0; cf < 2; cf++)
        acc[rf][cf] = __builtin_amdgcn_mfma_f32_16x16x32_bf16(af[rf], bf[cf], acc[rf][cf], 0, 0, 0);
    __syncthreads();
  }
#pragma unroll
  for (int rf = 0; rf < 2; rf++)
#pragma unroll
    for (int cf = 0; cf < 2; cf++) {
      int col = col0 + wc * 32 + cf * 16 + l16;
      float vb = bias ? bias[col] : 0.0f;
#pragma unroll
      for (int r = 0; r < 4; r++) {
        int row = row0 + wr * 32 + rf * 16 + quad * 4 + r;
        C[(size_t)row * N + col] = acc[rf][cf][r] + vb;
      }
    }
}

// ---------- prep: q fp32 -> qfrag[bh][rt=(m*16+it)][ks][lane][8] (fragment order) ----------
__global__ __launch_bounds__(256) void k_prep_qfrag(const float* __restrict__ q, short* __restrict__ qfrag) {
  int c = blockIdx.x * 256 + threadIdx.x;   // 262144 chunks
  int lane = c & 63, ks = (c >> 6) & 1, rt = (c >> 7) & 127, bh = c >> 14;
  int b = bh >> 3, h = bh & 7;
  int m = rt >> 4, i = ((rt & 15) << 4) + (lane & 15);
  int d = ks * 32 + (lane >> 4) * 8;
  const float* src = q + (size_t)((b * 256 + i) * 8 + m) * 512 + h * 64 + d;
  float4 f0 = *(const float4*)src, f1 = *(const float4*)(src + 4);
  bf16x8 o;
  o[0] = f2bf(f0.x); o[1] = f2bf(f0.y); o[2] = f2bf(f0.z); o[3] = f2bf(f0.w);
  o[4] = f2bf(f1.x); o[5] = f2bf(f1.y); o[6] = f2bf(f1.z); o[7] = f2bf(f1.w);
  *(bf16x8*)(qfrag + (size_t)c * 8) = o;
}

// ---------- prep: kv k-part -> kfrag[bh][rt=(z*16+jt)][ks][lane][8] ----------
__global__ __launch_bounds__(256) void k_prep_kfrag(const float* __restrict__ kv, short* __restrict__ kfrag) {
  int c = blockIdx.x * 256 + threadIdx.x;
  int lane = c & 63, ks = (c >> 6) & 1, rt = (c >> 7) & 127, bh = c >> 14;
  int b = bh >> 3, h = bh & 7;
  int z = rt >> 4, j = ((rt & 15) << 4) + (lane & 15);
  int d = ks * 32 + (lane >> 4) * 8;
  const float* src = kv + (size_t)((b * 256 + j) * 8 + z) * 1024 + h * 64 + d;
  float4 f0 = *(const float4*)src, f1 = *(const float4*)(src + 4);
  bf16x8 o;
  o[0] = f2bf(f0.x); o[1] = f2bf(f0.y); o[2] = f2bf(f0.z); o[3] = f2bf(f0.w);
  o[4] = f2bf(f1.x); o[5] = f2bf(f1.y); o[6] = f2bf(f1.z); o[7] = f2bf(f1.w);
  *(bf16x8*)(kfrag + (size_t)c * 8) = o;
}

// ---------- prep: kv v-part -> vfrag[bh][jc][m0][dt][jf][lane][8] (PV A-operand order) ----------
// element e of lane (quad,l16): V[m=2*m0+(e>>2)][j=jc*32+jf*16+quad*4+(e&3)][d=dt*16+l16]
__global__ __launch_bounds__(256) void k_prep_vfrag(const float* __restrict__ kv, short* __restrict__ vfrag) {
  __shared__ float Vs[256 * 66];
  int jc = blockIdx.x, bh = blockIdx.y;
  int b = bh >> 3, h = bh & 7;
  int t = threadIdx.x;
#pragma unroll
  for (int cc = 0; cc < 16; cc++) {
    int c = cc * 256 + t;               // [0,4096) float4 chunks
    int row = c >> 4, ch = c & 15;      // row = m*32+jl
    int m = row >> 5, jl = row & 31;
    float4 f = *(const float4*)(kv + (size_t)((b * 256 + jc * 32 + jl) * 8 + m) * 1024 + 512 + h * 64 + ch * 4);
    *(float4*)&Vs[row * 66 + ch * 4] = f;
  }
  __syncthreads();
  int m0 = t >> 6, lane = t & 63, quad = lane >> 4, l16 = lane & 15;
#pragma unroll
  for (int dt = 0; dt < 4; dt++)
#pragma unroll
    for (int jf = 0; jf < 2; jf++) {
      bf16x8 o;
#pragma unroll
      for (int e = 0; e < 8; e++) {
        int row = (2 * m0 + (e >> 2)) * 32 + jf * 16 + quad * 4 + (e & 3);
        o[e] = f2bf(Vs[row * 66 + dt * 16 + l16]);
      }
      size_t cid = ((((size_t)(bh * 8 + jc) * 4 + m0) * 4 + dt) * 2 + jf) * 64 + lane;
      *(bf16x8*)(vfrag + cid * 8) = o;
    }
}

// ---------- attention pass 1: rdg[bh][m][col=(z,j)] = 1/sum_i exp(S*scale), all-coalesced ----------
__global__ __launch_bounds__(256) void k_attn_den3(const short* __restrict__ qfrag, const short* __restrict__ kfrag,
                                                   float* __restrict__ rdg) {
  int ct = blockIdx.x, bh = blockIdx.y;
  int t = threadIdx.x;
  int w = t >> 6, lane = t & 63;
  bf16x8 bfr[2];
#pragma unroll
  for (int ks = 0; ks < 2; ks++)
    bfr[ks] = *(const bf16x8*)(kfrag + ((size_t)((bh * 128 + ct * 4 + w) * 2 + ks)) * 512 + lane * 8);
  for (int m = 0; m < 8; m++) {
    float facc = 0.0f;
#pragma unroll 4
    for (int it2 = 0; it2 < 16; it2++) {
      const short* ap = qfrag + ((size_t)((bh * 128 + m * 16 + it2) * 2)) * 512 + lane * 8;
      bf16x8 a0 = *(const bf16x8*)ap;
      bf16x8 a1 = *(const bf16x8*)(ap + 512);
      f32x4 c = {0, 0, 0, 0};
      c = __builtin_amdgcn_mfma_f32_16x16x32_bf16(a0, bfr[0], c, 0, 0, 0);
      c = __builtin_amdgcn_mfma_f32_16x16x32_bf16(a1, bfr[1], c, 0, 0, 0);
#pragma unroll
      for (int r = 0; r < 4; r++) facc += __expf(c[r] * SCALE_);
    }
    facc += __shfl_xor(facc, 16);
    facc += __shfl_xor(facc, 32);
    if (lane < 16)
      rdg[(size_t)(bh * 8 + m) * 2048 + ct * 64 + w * 16 + lane] = 1.0f / facc;
  }
}

// ---------- attention pass 2: all operands in fragment order; no LDS/barriers in j-loop ----------
// grid (zp 4, it 16, bh 16); wave w = m-pair {2w, 2w+1}
__global__ __launch_bounds__(256) void k_attn_out3(const short* __restrict__ qfrag, const short* __restrict__ kfrag,
                                                   const short* __restrict__ vfrag, const float* __restrict__ rdg,
                                                   short* __restrict__ ao) {
  __shared__ float red[4 * 64 * 17];
  int zp = blockIdx.x, it = blockIdx.y, bh = blockIdx.z;
  int b = bh >> 3, h = bh & 7;
  int i0 = it * 16;
  int t = threadIdx.x, w = t >> 6, lane = t & 63, quad = lane >> 4, l16 = lane & 15;
  const float* rb = rdg + (size_t)bh * 16384;
  // Q B-frags (const per block)
  bf16x8 qf[2][2];
#pragma unroll
  for (int mm = 0; mm < 2; mm++)
#pragma unroll
    for (int ks = 0; ks < 2; ks++)
      qf[mm][ks] = *(const bf16x8*)(qfrag + ((size_t)((bh * 128 + (2 * w + mm) * 16 + it) * 2 + ks)) * 512 + lane * 8);
  f32x4 acc[2][4] = {{{0,0,0,0},{0,0,0,0},{0,0,0,0},{0,0,0,0}},
                     {{0,0,0,0},{0,0,0,0},{0,0,0,0},{0,0,0,0}}};
  for (int jc = 0; jc < 8; jc++) {
    // V A-frags for this j-chunk (shared across z2), coalesced
    bf16x8 vf[4][2];
#pragma unroll
    for (int dt = 0; dt < 4; dt++)
#pragma unroll
      for (int jf = 0; jf < 2; jf++)
        vf[dt][jf] = *(const bf16x8*)(vfrag + ((((size_t)(bh * 8 + jc) * 4 + w) * 4 + dt) * 2 + jf) * 512 + lane * 8);
#pragma unroll
    for (int z2 = 0; z2 < 2; z2++) {
      int z = zp * 2 + z2;
      f32x4 c[2][2] = {{{0,0,0,0},{0,0,0,0}},{{0,0,0,0},{0,0,0,0}}};
#pragma unroll
      for (int jf = 0; jf < 2; jf++) {
        const short* kp = kfrag + ((size_t)((bh * 128 + z * 16 + jc * 2 + jf) * 2)) * 512 + lane * 8;
        bf16x8 k0 = *(const bf16x8*)kp;
        bf16x8 k1 = *(const bf16x8*)(kp + 512);
#pragma unroll
        for (int mm = 0; mm < 2; mm++) {
          c[jf][mm] = __builtin_amdgcn_mfma_f32_16x16x32_bf16(k0, qf[mm][0], c[jf][mm], 0, 0, 0);
          c[jf][mm] = __builtin_amdgcn_mfma_f32_16x16x32_bf16(k1, qf[mm][1], c[jf][mm], 0, 0, 0);
        }
      }
      bf16x8 pf[2];
#pragma unroll
      for (int jf = 0; jf < 2; jf++) {
        float4 rv0 = *(const float4*)(rb + (size_t)(2 * w) * 2048 + z * 256 + jc * 32 + jf * 16 + quad * 4);
        float4 rv1 = *(const float4*)(rb + (size_t)(2 * w + 1) * 2048 + z * 256 + jc * 32 + jf * 16 + quad * 4);
        float r0a[4] = {rv0.x, rv0.y, rv0.z, rv0.w};
        float r1a[4] = {rv1.x, rv1.y, rv1.z, rv1.w};
#pragma unroll
        for (int e = 0; e < 4; e++) {
          pf[jf][e]     = f2bf(__expf(c[jf][0][e] * SCALE_) * r0a[e]);
          pf[jf][e + 4] = f2bf(__expf(c[jf][1][e] * SCALE_) * r1a[e]);
        }
      }
#pragma unroll
      for (int dt = 0; dt < 4; dt++)
#pragma unroll
        for (int jf = 0; jf < 2; jf++)
          acc[z2][dt] = __builtin_amdgcn_mfma_f32_16x16x32_bf16(vf[dt][jf], pf[jf], acc[z2][dt], 0, 0, 0);
    }
  }
  // cross-wave (m-pair) reduction + store, per z2
  for (int z2 = 0; z2 < 2; z2++) {
    int z = zp * 2 + z2;
#pragma unroll
    for (int dt = 0; dt < 4; dt++)
#pragma unroll
      for (int r = 0; r < 4; r++)
        red[w * 1088 + (dt * 16 + quad * 4 + r) * 17 + l16] = acc[z2][dt][r];
    __syncthreads();
    {
      int i = t >> 4, dg = t & 15;
      float s[4] = {0, 0, 0, 0};
#pragma unroll
      for (int w2 = 0; w2 < 4; w2++)
#pragma unroll
        for (int r2 = 0; r2 < 4; r2++)
          s[r2] += red[w2 * 1088 + (dg * 4 + r2) * 17 + i];
      bf16x4 ov;
#pragma unroll
      for (int r2 = 0; r2 < 4; r2++) ov[r2] = f2bf(s[r2]);
      *(bf16x4*)(ao + (size_t)((b * 256 + i0 + i) * 8 + z) * 512 + h * 64 + dg * 4) = ov;
    }
    __syncthreads();
  }
}

// ---------- fused residual + layernorm; optional bf16 copy ----------
__global__ __launch_bounds__(256) void k_ln(const float* __restrict__ X, const float* __restrict__ R,
                                            const float* __restrict__ g, const float* __restrict__ be,
                                            float* __restrict__ Y, short* __restrict__ Ybf) {
  __shared__ float sm[8];
  int row = blockIdx.x, t = threadIdx.x;
  int lane = t & 63, w = t >> 6;
  size_t base = (size_t)row * 256;
  float v = X[base + t] + R[base + t];
  float s = v;
  s += __shfl_xor(s, 1); s += __shfl_xor(s, 2); s += __shfl_xor(s, 4);
  s += __shfl_xor(s, 8); s += __shfl_xor(s, 16); s += __shfl_xor(s, 32);
  if (lane == 0) sm[w] = s;
  __syncthreads();
  float mu = (sm[0] + sm[1] + sm[2] + sm[3]) * (1.0f / 256.0f);
  float dv = v - mu;
  float s2 = dv * dv;
  s2 += __shfl_xor(s2, 1); s2 += __shfl_xor(s2, 2); s2 += __shfl_xor(s2, 4);
  s2 += __shfl_xor(s2, 8); s2 += __shfl_xor(s2, 16); s2 += __shfl_xor(s2, 32);
  if (lane == 0) sm[4 + w] = s2;
  __syncthreads();
  float var = (sm[4] + sm[5] + sm[6] + sm[7]) * (1.0f / 256.0f);
  float rs = rsqrtf(var + 1e-5f);
  float res = dv * rs * g[t] + be[t];
  Y[base + t] = res;
  if (Ybf) Ybf[base + t] = f2bf(res);
}

// ---------- GEGLU -> bf16 ----------
__global__ __launch_bounds__(256) void k_geglu(const float* __restrict__ hg, short* __restrict__ gg) {
  int idx = blockIdx.x * 256 + threadIdx.x;
  int r = idx >> 10, c = idx & 1023;
  float a = hg[(size_t)r * 2048 + c];
  float gt = hg[(size_t)r * 2048 + 1024 + c];
  float ge = 0.5f * gt * (1.0f + erff(gt * 0.70710678118654752f));
  gg[idx] = f2bf(a * ge);
}

extern "C" void kernel_launch(void* const* d_in, const int* in_sizes, int n_in,
                              void* d_out, int out_size, void* d_ws, size_t ws_size,
                              hipStream_t stream) {
  const float* x    = (const float*)d_in[0];
  const float* Wq   = (const float*)d_in[1];
  const float* Wkv  = (const float*)d_in[2];
  const float* Wout = (const float*)d_in[3];
  const float* bout = (const float*)d_in[4];
  const float* g1   = (const float*)d_in[5];
  const float* be1  = (const float*)d_in[6];
  const float* Wff1 = (const float*)d_in[7];
  const float* bff1 = (const float*)d_in[8];
  const float* Wff2 = (const float*)d_in[9];
  const float* bff2 = (const float*)d_in[10];
  const float* g2   = (const float*)d_in[11];
  const float* be2  = (const float*)d_in[12];
  float* out = (float*)d_out;
  float* w = (float*)d_ws;

  // fp32 zone
  float* xt  = w;              // 1,048,576
  float* q   = w + 1048576;    // 2,097,152
  float* kv  = w + 3145728;    // 4,194,304
  float* hg  = w + 1048576;    // 8,388,608 (aliases q..kv+, dead before ff1)
  float* y   = w + 9437184;    // 1,048,576
  float* o   = w + 10485760;   // 1,048,576 (reused as ff)
  float* ff  = w + 10485760;
  float* rdg = w + 11534336;   //   262,144  [bh*8+m][2048]
  // bf16 zone
  short* sb     = (short*)(w + 11796480);
  short* qfrag  = sb;                    // 2,097,152  [bh][rt][ks][lane][8]
  short* kfrag  = sb + 2097152;          // 2,097,152
  short* vfrag  = sb + 4194304;          // 2,097,152  [bh][jc][m0][dt][jf][lane][8]
  short* xt_bf  = sb + 6291456;          // 1,048,576
  short* ao_bf  = sb + 7340032;          // 2,097,152
  short* y_bf   = sb + 9437184;          // 1,048,576
  short* gg_bf  = sb + 10485760;         // 4,194,304
  short* WqT    = sb + 14680064;
  short* WkvT   = sb + 14811136;
  short* WoutT  = sb + 15073280;
  short* Wff1T  = sb + 23461888;
  short* Wff2T  = sb + 23986176;

  k_transpose<<<dim3(8, 8, 16), dim3(32, 8), 0, stream>>>(x, xt, xt_bf);
  k_wt<<<dim3(16, 8), 256, 0, stream>>>(Wq, WqT, 256, 512);
  k_wt<<<dim3(32, 8), 256, 0, stream>>>(Wkv, WkvT, 256, 1024);
  k_wt<<<dim3(64, 128), 256, 0, stream>>>(Wout, WoutT, 4096, 2048);
  k_wt<<<dim3(64, 8), 256, 0, stream>>>(Wff1, Wff1T, 256, 2048);
  k_wt<<<dim3(8, 32), 256, 0, stream>>>(Wff2, Wff2T, 1024, 256);
  k_gemm_bf<<<dim3(8, 64), 256, 0, stream>>>(xt_bf, WqT, nullptr, q, 4096, 512, 256);
  k_gemm_bf<<<dim3(16, 64), 256, 0, stream>>>(xt_bf, WkvT, nullptr, kv, 4096, 1024, 256);
  k_prep_qfrag<<<1024, 256, 0, stream>>>(q, qfrag);
  k_prep_kfrag<<<1024, 256, 0, stream>>>(kv, kfrag);
  k_prep_vfrag<<<dim3(8, 16), 256, 0, stream>>>(kv, vfrag);
  k_attn_den3<<<dim3(32, 16), 256, 0, stream>>>(qfrag, kfrag, rdg);
  k_attn_out3<<<dim3(4, 16, 16), 256, 0, stream>>>(qfrag, kfrag, vfrag, rdg, ao_bf);
  k_gemm_bf<<<dim3(32, 8), 256, 0, stream>>>(ao_bf, WoutT, bout, o, 512, 2048, 4096);
  k_ln<<<4096, 256, 0, stream>>>(xt, o, g1, be1, y, y_bf);
  k_gemm_bf<<<dim3(32, 64), 256, 0, stream>>>(y_bf, Wff1T, bff1, hg, 4096, 2048, 256);
  k_geglu<<<16384, 256, 0, stream>>>(hg, gg_bf);
  k_gemm_bf<<<dim3(4, 64), 256, 0, stream>>>(gg_bf, Wff2T, bff2, ff, 4096, 256, 1024);
  k_ln<<<4096, 256, 0, stream>>>(y, ff, g2, be2, out, nullptr);
}

// Round 6
// 281.728 us; speedup vs baseline: 1.6145x; 1.1153x over previous
//
#include <hip/hip_runtime.h>
#include <math.h>

#define SCALE_ 0.125f

typedef __attribute__((ext_vector_type(8))) short bf16x8;
typedef __attribute__((ext_vector_type(4))) short bf16x4;
typedef __attribute__((ext_vector_type(4))) float f32x4;

__device__ inline short f2bf(float f) {
  unsigned u = __builtin_bit_cast(unsigned, f);
  u += 0x7fff + ((u >> 16) & 1);
  return (short)(u >> 16);
}

// ---------- transpose x [B,D,M,N] -> xt [B,N,M,D] fp32 + bf16 ----------
__global__ __launch_bounds__(256) void k_transpose(const float* __restrict__ x, float* __restrict__ xt,
                                                   short* __restrict__ xtbf) {
  __shared__ float tile[32][33];
  int bm = blockIdx.z; int b = bm >> 3; int m = bm & 7;
  int d0 = blockIdx.x * 32, n0 = blockIdx.y * 32;
#pragma unroll
  for (int r = 0; r < 32; r += 8) {
    int d = d0 + threadIdx.y + r, n = n0 + threadIdx.x;
    tile[threadIdx.y + r][threadIdx.x] = x[((size_t)(b * 256 + d) * 8 + m) * 256 + n];
  }
  __syncthreads();
#pragma unroll
  for (int r = 0; r < 32; r += 8) {
    int n = n0 + threadIdx.y + r, d = d0 + threadIdx.x;
    float v = tile[threadIdx.x][threadIdx.y + r];
    size_t idx = ((size_t)(b * 256 + n) * 8 + m) * 256 + d;
    xt[idx] = v;
    xtbf[idx] = f2bf(v);
  }
}

// ---------- weight transpose+convert: W fp32 [K][N] -> WT bf16 [N][K] ----------
__global__ __launch_bounds__(256) void k_wt(const float* __restrict__ W, short* __restrict__ WT, int K, int N) {
  __shared__ float tile[32][33];
  int n0 = blockIdx.x * 32, k0 = blockIdx.y * 32;
  int tx = threadIdx.x & 31, ty = threadIdx.x >> 5;
#pragma unroll
  for (int r = 0; r < 32; r += 8)
    tile[ty + r][tx] = W[(size_t)(k0 + ty + r) * N + n0 + tx];
  __syncthreads();
#pragma unroll
  for (int r = 0; r < 32; r += 8)
    WT[(size_t)(n0 + ty + r) * K + k0 + tx] = f2bf(tile[tx][ty + r]);
}

// ---------- bf16 MFMA GEMM with split-K + register-prefetch pipeline ----------
// C_partial[kp][M][N]; kp = blockIdx.z over K range [kp*Ks, (kp+1)*Ks); bias added by kp==0
__global__ __launch_bounds__(256) void k_gemm_bf(const short* __restrict__ A, const short* __restrict__ Bt,
                                                 const float* __restrict__ bias, float* __restrict__ C,
                                                 int M, int N, int K, int Ks) {
  __shared__ short As[64 * 40];
  __shared__ short Bs[64 * 40];
  int t = threadIdx.x;
  int row0 = blockIdx.y * 64, col0 = blockIdx.x * 64;
  int kp = blockIdx.z;
  int kbeg = kp * Ks, kend = kbeg + Ks;
  int w = t >> 6, lane = t & 63, quad = lane >> 4, l16 = lane & 15;
  int wr = w >> 1, wc = w & 1;
  int lrow = t >> 2, lch = (t & 3) * 8;
  const short* Ap = A + (size_t)(row0 + lrow) * K + lch;
  const short* Bp = Bt + (size_t)(col0 + lrow) * K + lch;
  f32x4 acc[2][2] = {{{0,0,0,0},{0,0,0,0}},{{0,0,0,0},{0,0,0,0}}};
  bf16x8 av = *(const bf16x8*)(Ap + kbeg);
  bf16x8 bv = *(const bf16x8*)(Bp + kbeg);
  for (int k0 = kbeg; k0 < kend; k0 += 32) {
    *(bf16x8*)&As[lrow * 40 + lch] = av;
    *(bf16x8*)&Bs[lrow * 40 + lch] = bv;
    __syncthreads();
    if (k0 + 32 < kend) {           // prefetch next tile while computing this one
      av = *(const bf16x8*)(Ap + k0 + 32);
      bv = *(const bf16x8*)(Bp + k0 + 32);
    }
    bf16x8 af[2], bf[2];
#pragma unroll
    for (int rf = 0; rf < 2; rf++) af[rf] = *(const bf16x8*)&As[(wr * 32 + rf * 16 + l16) * 40 + quad * 8];
#pragma unroll
    for (int cf = 0; cf < 2; cf++) bf[cf] = *(const bf16x8*)&Bs[(wc * 32 + cf * 16 + l16) * 40 + quad * 8];
#pragma unroll
    for (int rf = 0; rf < 2; rf++)
#pragma unroll
      for (int cf = 0; cf < 2; cf++)
        acc[rf][cf] = __builtin_amdgcn_mfma_f32_16x16x32_bf16(af[rf], bf[cf], acc[rf][cf], 0, 0, 0);
    __syncthreads();
  }
  float* Cp = C + (size_t)kp * M * N;
#pragma unroll
  for (int rf = 0; rf < 2; rf++)
#pragma unroll
    for (int cf = 0; cf < 2; cf++) {
      int col = col0 + wc * 32 + cf * 16 + l16;
      float vb = (bias && kp == 0) ? bias[col] : 0.0f;
#pragma unroll
      for (int r = 0; r < 4; r++) {
        int row = row0 + wr * 32 + rf * 16 + quad * 4 + r;
        Cp[(size_t)row * N + col] = acc[rf][cf][r] + vb;
      }
    }
}

// ---------- prep: q fp32 -> qfrag[bh][rt=(m*16+it)][ks][lane][8] (fragment order) ----------
__global__ __launch_bounds__(256) void k_prep_qfrag(const float* __restrict__ q, short* __restrict__ qfrag) {
  int c = blockIdx.x * 256 + threadIdx.x;
  int lane = c & 63, ks = (c >> 6) & 1, rt = (c >> 7) & 127, bh = c >> 14;
  int b = bh >> 3, h = bh & 7;
  int m = rt >> 4, i = ((rt & 15) << 4) + (lane & 15);
  int d = ks * 32 + (lane >> 4) * 8;
  const float* src = q + (size_t)((b * 256 + i) * 8 + m) * 512 + h * 64 + d;
  float4 f0 = *(const float4*)src, f1 = *(const float4*)(src + 4);
  bf16x8 o;
  o[0] = f2bf(f0.x); o[1] = f2bf(f0.y); o[2] = f2bf(f0.z); o[3] = f2bf(f0.w);
  o[4] = f2bf(f1.x); o[5] = f2bf(f1.y); o[6] = f2bf(f1.z); o[7] = f2bf(f1.w);
  *(bf16x8*)(qfrag + (size_t)c * 8) = o;
}

// ---------- prep: kv k-part -> kfrag[bh][rt=(z*16+jt)][ks][lane][8] ----------
__global__ __launch_bounds__(256) void k_prep_kfrag(const float* __restrict__ kv, short* __restrict__ kfrag) {
  int c = blockIdx.x * 256 + threadIdx.x;
  int lane = c & 63, ks = (c >> 6) & 1, rt = (c >> 7) & 127, bh = c >> 14;
  int b = bh >> 3, h = bh & 7;
  int z = rt >> 4, j = ((rt & 15) << 4) + (lane & 15);
  int d = ks * 32 + (lane >> 4) * 8;
  const float* src = kv + (size_t)((b * 256 + j) * 8 + z) * 1024 + h * 64 + d;
  float4 f0 = *(const float4*)src, f1 = *(const float4*)(src + 4);
  bf16x8 o;
  o[0] = f2bf(f0.x); o[1] = f2bf(f0.y); o[2] = f2bf(f0.z); o[3] = f2bf(f0.w);
  o[4] = f2bf(f1.x); o[5] = f2bf(f1.y); o[6] = f2bf(f1.z); o[7] = f2bf(f1.w);
  *(bf16x8*)(kfrag + (size_t)c * 8) = o;
}

// ---------- prep: kv v-part -> vfrag[bh][jc][m0][dt][jf][lane][8] (PV A-operand order) ----------
__global__ __launch_bounds__(256) void k_prep_vfrag(const float* __restrict__ kv, short* __restrict__ vfrag) {
  __shared__ float Vs[256 * 66];
  int jc = blockIdx.x, bh = blockIdx.y;
  int b = bh >> 3, h = bh & 7;
  int t = threadIdx.x;
#pragma unroll
  for (int cc = 0; cc < 16; cc++) {
    int c = cc * 256 + t;
    int row = c >> 4, ch = c & 15;
    int m = row >> 5, jl = row & 31;
    float4 f = *(const float4*)(kv + (size_t)((b * 256 + jc * 32 + jl) * 8 + m) * 1024 + 512 + h * 64 + ch * 4);
    *(float4*)&Vs[row * 66 + ch * 4] = f;
  }
  __syncthreads();
  int m0 = t >> 6, lane = t & 63, quad = lane >> 4, l16 = lane & 15;
#pragma unroll
  for (int dt = 0; dt < 4; dt++)
#pragma unroll
    for (int jf = 0; jf < 2; jf++) {
      bf16x8 o;
#pragma unroll
      for (int e = 0; e < 8; e++) {
        int row = (2 * m0 + (e >> 2)) * 32 + jf * 16 + quad * 4 + (e & 3);
        o[e] = f2bf(Vs[row * 66 + dt * 16 + l16]);
      }
      size_t cid = ((((size_t)(bh * 8 + jc) * 4 + m0) * 4 + dt) * 2 + jf) * 64 + lane;
      *(bf16x8*)(vfrag + cid * 8) = o;
    }
}

// ---------- attention pass 1: rdg[bh][m][col=(z,j)] ----------
__global__ __launch_bounds__(256) void k_attn_den3(const short* __restrict__ qfrag, const short* __restrict__ kfrag,
                                                   float* __restrict__ rdg) {
  int ct = blockIdx.x, bh = blockIdx.y;
  int t = threadIdx.x;
  int w = t >> 6, lane = t & 63;
  bf16x8 bfr[2];
#pragma unroll
  for (int ks = 0; ks < 2; ks++)
    bfr[ks] = *(const bf16x8*)(kfrag + ((size_t)((bh * 128 + ct * 4 + w) * 2 + ks)) * 512 + lane * 8);
  for (int m = 0; m < 8; m++) {
    float facc = 0.0f;
#pragma unroll 4
    for (int it2 = 0; it2 < 16; it2++) {
      const short* ap = qfrag + ((size_t)((bh * 128 + m * 16 + it2) * 2)) * 512 + lane * 8;
      bf16x8 a0 = *(const bf16x8*)ap;
      bf16x8 a1 = *(const bf16x8*)(ap + 512);
      f32x4 c = {0, 0, 0, 0};
      c = __builtin_amdgcn_mfma_f32_16x16x32_bf16(a0, bfr[0], c, 0, 0, 0);
      c = __builtin_amdgcn_mfma_f32_16x16x32_bf16(a1, bfr[1], c, 0, 0, 0);
#pragma unroll
      for (int r = 0; r < 4; r++) facc += __expf(c[r] * SCALE_);
    }
    facc += __shfl_xor(facc, 16);
    facc += __shfl_xor(facc, 32);
    if (lane < 16)
      rdg[(size_t)(bh * 8 + m) * 2048 + ct * 64 + w * 16 + lane] = 1.0f / facc;
  }
}

// ---------- attention pass 2: register-direct P, fragment-order operands ----------
__global__ __launch_bounds__(256) void k_attn_out3(const short* __restrict__ qfrag, const short* __restrict__ kfrag,
                                                   const short* __restrict__ vfrag, const float* __restrict__ rdg,
                                                   short* __restrict__ ao) {
  __shared__ float red[4 * 64 * 17];
  int zp = blockIdx.x, it = blockIdx.y, bh = blockIdx.z;
  int b = bh >> 3, h = bh & 7;
  int i0 = it * 16;
  int t = threadIdx.x, w = t >> 6, lane = t & 63, quad = lane >> 4, l16 = lane & 15;
  const float* rb = rdg + (size_t)bh * 16384;
  bf16x8 qf[2][2];
#pragma unroll
  for (int mm = 0; mm < 2; mm++)
#pragma unroll
    for (int ks = 0; ks < 2; ks++)
      qf[mm][ks] = *(const bf16x8*)(qfrag + ((size_t)((bh * 128 + (2 * w + mm) * 16 + it) * 2 + ks)) * 512 + lane * 8);
  f32x4 acc[2][4] = {{{0,0,0,0},{0,0,0,0},{0,0,0,0},{0,0,0,0}},
                     {{0,0,0,0},{0,0,0,0},{0,0,0,0},{0,0,0,0}}};
  for (int jc = 0; jc < 8; jc++) {
    bf16x8 vf[4][2];
#pragma unroll
    for (int dt = 0; dt < 4; dt++)
#pragma unroll
      for (int jf = 0; jf < 2; jf++)
        vf[dt][jf] = *(const bf16x8*)(vfrag + ((((size_t)(bh * 8 + jc) * 4 + w) * 4 + dt) * 2 + jf) * 512 + lane * 8);
#pragma unroll
    for (int z2 = 0; z2 < 2; z2++) {
      int z = zp * 2 + z2;
      f32x4 c[2][2] = {{{0,0,0,0},{0,0,0,0}},{{0,0,0,0},{0,0,0,0}}};
#pragma unroll
      for (int jf = 0; jf < 2; jf++) {
        const short* kp = kfrag + ((size_t)((bh * 128 + z * 16 + jc * 2 + jf) * 2)) * 512 + lane * 8;
        bf16x8 k0 = *(const bf16x8*)kp;
        bf16x8 k1 = *(const bf16x8*)(kp + 512);
#pragma unroll
        for (int mm = 0; mm < 2; mm++) {
          c[jf][mm] = __builtin_amdgcn_mfma_f32_16x16x32_bf16(k0, qf[mm][0], c[jf][mm], 0, 0, 0);
          c[jf][mm] = __builtin_amdgcn_mfma_f32_16x16x32_bf16(k1, qf[mm][1], c[jf][mm], 0, 0, 0);
        }
      }
      bf16x8 pf[2];
#pragma unroll
      for (int jf = 0; jf < 2; jf++) {
        float4 rv0 = *(const float4*)(rb + (size_t)(2 * w) * 2048 + z * 256 + jc * 32 + jf * 16 + quad * 4);
        float4 rv1 = *(const float4*)(rb + (size_t)(2 * w + 1) * 2048 + z * 256 + jc * 32 + jf * 16 + quad * 4);
        float r0a[4] = {rv0.x, rv0.y, rv0.z, rv0.w};
        float r1a[4] = {rv1.x, rv1.y, rv1.z, rv1.w};
#pragma unroll
        for (int e = 0; e < 4; e++) {
          pf[jf][e]     = f2bf(__expf(c[jf][0][e] * SCALE_) * r0a[e]);
          pf[jf][e + 4] = f2bf(__expf(c[jf][1][e] * SCALE_) * r1a[e]);
        }
      }
#pragma unroll
      for (int dt = 0; dt < 4; dt++)
#pragma unroll
        for (int jf = 0; jf < 2; jf++)
          acc[z2][dt] = __builtin_amdgcn_mfma_f32_16x16x32_bf16(vf[dt][jf], pf[jf], acc[z2][dt], 0, 0, 0);
    }
  }
  for (int z2 = 0; z2 < 2; z2++) {
    int z = zp * 2 + z2;
#pragma unroll
    for (int dt = 0; dt < 4; dt++)
#pragma unroll
      for (int r = 0; r < 4; r++)
        red[w * 1088 + (dt * 16 + quad * 4 + r) * 17 + l16] = acc[z2][dt][r];
    __syncthreads();
    {
      int i = t >> 4, dg = t & 15;
      float s[4] = {0, 0, 0, 0};
#pragma unroll
      for (int w2 = 0; w2 < 4; w2++)
#pragma unroll
        for (int r2 = 0; r2 < 4; r2++)
          s[r2] += red[w2 * 1088 + (dg * 4 + r2) * 17 + i];
      bf16x4 ov;
#pragma unroll
      for (int r2 = 0; r2 < 4; r2++) ov[r2] = f2bf(s[r2]);
      *(bf16x4*)(ao + (size_t)((b * 256 + i0 + i) * 8 + z) * 512 + h * 64 + dg * 4) = ov;
    }
    __syncthreads();
  }
}

// ---------- fused residual(np split-K partials) + layernorm; optional bf16 copy ----------
__global__ __launch_bounds__(256) void k_ln(const float* __restrict__ X, const float* __restrict__ P, int np,
                                            const float* __restrict__ g, const float* __restrict__ be,
                                            float* __restrict__ Y, short* __restrict__ Ybf) {
  __shared__ float sm[8];
  int row = blockIdx.x, t = threadIdx.x;
  int lane = t & 63, w = t >> 6;
  size_t base = (size_t)row * 256;
  float v = X[base + t];
  for (int p = 0; p < np; p++) v += P[(size_t)p * 1048576 + base + t];
  float s = v;
  s += __shfl_xor(s, 1); s += __shfl_xor(s, 2); s += __shfl_xor(s, 4);
  s += __shfl_xor(s, 8); s += __shfl_xor(s, 16); s += __shfl_xor(s, 32);
  if (lane == 0) sm[w] = s;
  __syncthreads();
  float mu = (sm[0] + sm[1] + sm[2] + sm[3]) * (1.0f / 256.0f);
  float dv = v - mu;
  float s2 = dv * dv;
  s2 += __shfl_xor(s2, 1); s2 += __shfl_xor(s2, 2); s2 += __shfl_xor(s2, 4);
  s2 += __shfl_xor(s2, 8); s2 += __shfl_xor(s2, 16); s2 += __shfl_xor(s2, 32);
  if (lane == 0) sm[4 + w] = s2;
  __syncthreads();
  float var = (sm[4] + sm[5] + sm[6] + sm[7]) * (1.0f / 256.0f);
  float rs = rsqrtf(var + 1e-5f);
  float res = dv * rs * g[t] + be[t];
  Y[base + t] = res;
  if (Ybf) Ybf[base + t] = f2bf(res);
}

// ---------- GEGLU -> bf16 ----------
__global__ __launch_bounds__(256) void k_geglu(const float* __restrict__ hg, short* __restrict__ gg) {
  int idx = blockIdx.x * 256 + threadIdx.x;
  int r = idx >> 10, c = idx & 1023;
  float a = hg[(size_t)r * 2048 + c];
  float gt = hg[(size_t)r * 2048 + 1024 + c];
  float ge = 0.5f * gt * (1.0f + erff(gt * 0.70710678118654752f));
  gg[idx] = f2bf(a * ge);
}

extern "C" void kernel_launch(void* const* d_in, const int* in_sizes, int n_in,
                              void* d_out, int out_size, void* d_ws, size_t ws_size,
                              hipStream_t stream) {
  const float* x    = (const float*)d_in[0];
  const float* Wq   = (const float*)d_in[1];
  const float* Wkv  = (const float*)d_in[2];
  const float* Wout = (const float*)d_in[3];
  const float* bout = (const float*)d_in[4];
  const float* g1   = (const float*)d_in[5];
  const float* be1  = (const float*)d_in[6];
  const float* Wff1 = (const float*)d_in[7];
  const float* bff1 = (const float*)d_in[8];
  const float* Wff2 = (const float*)d_in[9];
  const float* bff2 = (const float*)d_in[10];
  const float* g2   = (const float*)d_in[11];
  const float* be2  = (const float*)d_in[12];
  float* out = (float*)d_out;
  float* w = (float*)d_ws;

  // fp32 zone. The region w+1048576 .. w+9437184 (8.4M floats) is time-multiplexed:
  //   phase A: q [2M] + kv [4.2M]        (QKV gemms -> preps)
  //   phase B: Wout split-K partials 4×1M (Wout gemm -> LN1)
  //   phase C: hg [8.4M]                  (ff1 gemm -> geglu)
  //   phase D: ff2 split-K partials 4×1M  (ff2 gemm -> LN2)
  float* xt   = w;              // 1,048,576
  float* q    = w + 1048576;
  float* kv   = w + 3145728;
  float* part = w + 1048576;    // split-K partials (phases B and D)
  float* hg   = w + 1048576;
  float* y    = w + 9437184;    // 1,048,576
  float* rdg  = w + 11534336;   //   262,144
  // bf16 zone
  short* sb     = (short*)(w + 11796480);
  short* qfrag  = sb;                    // 2,097,152
  short* kfrag  = sb + 2097152;          // 2,097,152
  short* vfrag  = sb + 4194304;          // 2,097,152
  short* xt_bf  = sb + 6291456;          // 1,048,576
  short* ao_bf  = sb + 7340032;          // 2,097,152
  short* y_bf   = sb + 9437184;          // 1,048,576
  short* gg_bf  = sb + 10485760;         // 4,194,304
  short* WqT    = sb + 14680064;
  short* WkvT   = sb + 14811136;
  short* WoutT  = sb + 15073280;
  short* Wff1T  = sb + 23461888;
  short* Wff2T  = sb + 23986176;

  k_transpose<<<dim3(8, 8, 16), dim3(32, 8), 0, stream>>>(x, xt, xt_bf);
  k_wt<<<dim3(16, 8), 256, 0, stream>>>(Wq, WqT, 256, 512);
  k_wt<<<dim3(32, 8), 256, 0, stream>>>(Wkv, WkvT, 256, 1024);
  k_wt<<<dim3(64, 128), 256, 0, stream>>>(Wout, WoutT, 4096, 2048);
  k_wt<<<dim3(64, 8), 256, 0, stream>>>(Wff1, Wff1T, 256, 2048);
  k_wt<<<dim3(8, 32), 256, 0, stream>>>(Wff2, Wff2T, 1024, 256);
  k_gemm_bf<<<dim3(8, 64, 1), 256, 0, stream>>>(xt_bf, WqT, nullptr, q, 4096, 512, 256, 256);
  k_gemm_bf<<<dim3(16, 64, 1), 256, 0, stream>>>(xt_bf, WkvT, nullptr, kv, 4096, 1024, 256, 256);
  k_prep_qfrag<<<1024, 256, 0, stream>>>(q, qfrag);
  k_prep_kfrag<<<1024, 256, 0, stream>>>(kv, kfrag);
  k_prep_vfrag<<<dim3(8, 16), 256, 0, stream>>>(kv, vfrag);
  k_attn_den3<<<dim3(32, 16), 256, 0, stream>>>(qfrag, kfrag, rdg);
  k_attn_out3<<<dim3(4, 16, 16), 256, 0, stream>>>(qfrag, kfrag, vfrag, rdg, ao_bf);
  k_gemm_bf<<<dim3(32, 8, 4), 256, 0, stream>>>(ao_bf, WoutT, bout, part, 512, 2048, 4096, 1024);
  k_ln<<<4096, 256, 0, stream>>>(xt, part, 4, g1, be1, y, y_bf);
  k_gemm_bf<<<dim3(32, 64, 1), 256, 0, stream>>>(y_bf, Wff1T, bff1, hg, 4096, 2048, 256, 256);
  k_geglu<<<16384, 256, 0, stream>>>(hg, gg_bf);
  k_gemm_bf<<<dim3(4, 64, 4), 256, 0, stream>>>(gg_bf, Wff2T, bff2, part, 4096, 256, 1024, 256);
  k_ln<<<4096, 256, 0, stream>>>(y, part, 4, g2, be2, out, nullptr);
}

// Round 7
// 264.930 us; speedup vs baseline: 1.7169x; 1.0634x over previous
//
#include <hip/hip_runtime.h>
#include <math.h>

#define SCALE_ 0.125f
#define KS_ 0.1803368801111244f   // SCALE_ * log2(e)

typedef __attribute__((ext_vector_type(8))) short bf16x8;
typedef __attribute__((ext_vector_type(4))) short bf16x4;
typedef __attribute__((ext_vector_type(4))) float f32x4;

__device__ inline short f2bf(float f) {
  unsigned u = __builtin_bit_cast(unsigned, f);
  u += 0x7fff + ((u >> 16) & 1);
  return (short)(u >> 16);
}

// ---------- transpose x [B,D,M,N] -> xt [B,N,M,D] fp32 + bf16 ----------
__global__ __launch_bounds__(256) void k_transpose(const float* __restrict__ x, float* __restrict__ xt,
                                                   short* __restrict__ xtbf) {
  __shared__ float tile[32][33];
  int bm = blockIdx.z; int b = bm >> 3; int m = bm & 7;
  int d0 = blockIdx.x * 32, n0 = blockIdx.y * 32;
#pragma unroll
  for (int r = 0; r < 32; r += 8) {
    int d = d0 + threadIdx.y + r, n = n0 + threadIdx.x;
    tile[threadIdx.y + r][threadIdx.x] = x[((size_t)(b * 256 + d) * 8 + m) * 256 + n];
  }
  __syncthreads();
#pragma unroll
  for (int r = 0; r < 32; r += 8) {
    int n = n0 + threadIdx.y + r, d = d0 + threadIdx.x;
    float v = tile[threadIdx.x][threadIdx.y + r];
    size_t idx = ((size_t)(b * 256 + n) * 8 + m) * 256 + d;
    xt[idx] = v;
    xtbf[idx] = f2bf(v);
  }
}

// ---------- weight transpose+convert: W fp32 [K][N] -> WT bf16 [N][K] ----------
__global__ __launch_bounds__(256) void k_wt(const float* __restrict__ W, short* __restrict__ WT, int K, int N) {
  __shared__ float tile[32][33];
  int n0 = blockIdx.x * 32, k0 = blockIdx.y * 32;
  int tx = threadIdx.x & 31, ty = threadIdx.x >> 5;
#pragma unroll
  for (int r = 0; r < 32; r += 8)
    tile[ty + r][tx] = W[(size_t)(k0 + ty + r) * N + n0 + tx];
  __syncthreads();
#pragma unroll
  for (int r = 0; r < 32; r += 8)
    WT[(size_t)(n0 + ty + r) * K + k0 + tx] = f2bf(tile[tx][ty + r]);
}

// ---------- bf16 MFMA GEMM with split-K + register-prefetch pipeline ----------
__global__ __launch_bounds__(256) void k_gemm_bf(const short* __restrict__ A, const short* __restrict__ Bt,
                                                 const float* __restrict__ bias, float* __restrict__ C,
                                                 int M, int N, int K, int Ks) {
  __shared__ short As[64 * 40];
  __shared__ short Bs[64 * 40];
  int t = threadIdx.x;
  int row0 = blockIdx.y * 64, col0 = blockIdx.x * 64;
  int kp = blockIdx.z;
  int kbeg = kp * Ks, kend = kbeg + Ks;
  int w = t >> 6, lane = t & 63, quad = lane >> 4, l16 = lane & 15;
  int wr = w >> 1, wc = w & 1;
  int lrow = t >> 2, lch = (t & 3) * 8;
  const short* Ap = A + (size_t)(row0 + lrow) * K + lch;
  const short* Bp = Bt + (size_t)(col0 + lrow) * K + lch;
  f32x4 acc[2][2] = {{{0,0,0,0},{0,0,0,0}},{{0,0,0,0},{0,0,0,0}}};
  bf16x8 av = *(const bf16x8*)(Ap + kbeg);
  bf16x8 bv = *(const bf16x8*)(Bp + kbeg);
  for (int k0 = kbeg; k0 < kend; k0 += 32) {
    *(bf16x8*)&As[lrow * 40 + lch] = av;
    *(bf16x8*)&Bs[lrow * 40 + lch] = bv;
    __syncthreads();
    if (k0 + 32 < kend) {
      av = *(const bf16x8*)(Ap + k0 + 32);
      bv = *(const bf16x8*)(Bp + k0 + 32);
    }
    bf16x8 af[2], bf[2];
#pragma unroll
    for (int rf = 0; rf < 2; rf++) af[rf] = *(const bf16x8*)&As[(wr * 32 + rf * 16 + l16) * 40 + quad * 8];
#pragma unroll
    for (int cf = 0; cf < 2; cf++) bf[cf] = *(const bf16x8*)&Bs[(wc * 32 + cf * 16 + l16) * 40 + quad * 8];
#pragma unroll
    for (int rf = 0; rf < 2; rf++)
#pragma unroll
      for (int cf = 0; cf < 2; cf++)
        acc[rf][cf] = __builtin_amdgcn_mfma_f32_16x16x32_bf16(af[rf], bf[cf], acc[rf][cf], 0, 0, 0);
    __syncthreads();
  }
  float* Cp = C + (size_t)kp * M * N;
#pragma unroll
  for (int rf = 0; rf < 2; rf++)
#pragma unroll
    for (int cf = 0; cf < 2; cf++) {
      int col = col0 + wc * 32 + cf * 16 + l16;
      float vb = (bias && kp == 0) ? bias[col] : 0.0f;
#pragma unroll
      for (int r = 0; r < 4; r++) {
        int row = row0 + wr * 32 + rf * 16 + quad * 4 + r;
        Cp[(size_t)row * N + col] = acc[rf][cf][r] + vb;
      }
    }
}

// ---------- prep: q fp32 -> qfrag[bh][rt=(m*16+it)][ks][lane][8] ----------
__global__ __launch_bounds__(256) void k_prep_qfrag(const float* __restrict__ q, short* __restrict__ qfrag) {
  int c = blockIdx.x * 256 + threadIdx.x;
  int lane = c & 63, ks = (c >> 6) & 1, rt = (c >> 7) & 127, bh = c >> 14;
  int b = bh >> 3, h = bh & 7;
  int m = rt >> 4, i = ((rt & 15) << 4) + (lane & 15);
  int d = ks * 32 + (lane >> 4) * 8;
  const float* src = q + (size_t)((b * 256 + i) * 8 + m) * 512 + h * 64 + d;
  float4 f0 = *(const float4*)src, f1 = *(const float4*)(src + 4);
  bf16x8 o;
  o[0] = f2bf(f0.x); o[1] = f2bf(f0.y); o[2] = f2bf(f0.z); o[3] = f2bf(f0.w);
  o[4] = f2bf(f1.x); o[5] = f2bf(f1.y); o[6] = f2bf(f1.z); o[7] = f2bf(f1.w);
  *(bf16x8*)(qfrag + (size_t)c * 8) = o;
}

// ---------- prep: kv k-part -> kfrag[bh][rt=(z*16+jt)][ks][lane][8] ----------
__global__ __launch_bounds__(256) void k_prep_kfrag(const float* __restrict__ kv, short* __restrict__ kfrag) {
  int c = blockIdx.x * 256 + threadIdx.x;
  int lane = c & 63, ks = (c >> 6) & 1, rt = (c >> 7) & 127, bh = c >> 14;
  int b = bh >> 3, h = bh & 7;
  int z = rt >> 4, j = ((rt & 15) << 4) + (lane & 15);
  int d = ks * 32 + (lane >> 4) * 8;
  const float* src = kv + (size_t)((b * 256 + j) * 8 + z) * 1024 + h * 64 + d;
  float4 f0 = *(const float4*)src, f1 = *(const float4*)(src + 4);
  bf16x8 o;
  o[0] = f2bf(f0.x); o[1] = f2bf(f0.y); o[2] = f2bf(f0.z); o[3] = f2bf(f0.w);
  o[4] = f2bf(f1.x); o[5] = f2bf(f1.y); o[6] = f2bf(f1.z); o[7] = f2bf(f1.w);
  *(bf16x8*)(kfrag + (size_t)c * 8) = o;
}

// ---------- prep: kv v-part -> vfrag[bh][jc][m0][dt][jf][lane][8] ----------
__global__ __launch_bounds__(256) void k_prep_vfrag(const float* __restrict__ kv, short* __restrict__ vfrag) {
  __shared__ float Vs[256 * 66];
  int jc = blockIdx.x, bh = blockIdx.y;
  int b = bh >> 3, h = bh & 7;
  int t = threadIdx.x;
#pragma unroll
  for (int cc = 0; cc < 16; cc++) {
    int c = cc * 256 + t;
    int row = c >> 4, ch = c & 15;
    int m = row >> 5, jl = row & 31;
    float4 f = *(const float4*)(kv + (size_t)((b * 256 + jc * 32 + jl) * 8 + m) * 1024 + 512 + h * 64 + ch * 4);
    *(float4*)&Vs[row * 66 + ch * 4] = f;
  }
  __syncthreads();
  int m0 = t >> 6, lane = t & 63, quad = lane >> 4, l16 = lane & 15;
#pragma unroll
  for (int dt = 0; dt < 4; dt++)
#pragma unroll
    for (int jf = 0; jf < 2; jf++) {
      bf16x8 o;
#pragma unroll
      for (int e = 0; e < 8; e++) {
        int row = (2 * m0 + (e >> 2)) * 32 + jf * 16 + quad * 4 + (e & 3);
        o[e] = f2bf(Vs[row * 66 + dt * 16 + l16]);
      }
      size_t cid = ((((size_t)(bh * 8 + jc) * 4 + m0) * 4 + dt) * 2 + jf) * 64 + lane;
      *(bf16x8*)(vfrag + cid * 8) = o;
    }
}

// ---------- attention pass 1: rdg[bh][m][col=(z,j)] = -log2( sum_i 2^(S*KS) ) ----------
// grid (ct 32, mp 2, bh 16)
__global__ __launch_bounds__(256) void k_attn_den4(const short* __restrict__ qfrag, const short* __restrict__ kfrag,
                                                   float* __restrict__ rdg) {
  int ct = blockIdx.x, mp = blockIdx.y, bh = blockIdx.z;
  int t = threadIdx.x;
  int w = t >> 6, lane = t & 63;
  bf16x8 bfr[2];
#pragma unroll
  for (int ks = 0; ks < 2; ks++)
    bfr[ks] = *(const bf16x8*)(kfrag + ((size_t)((bh * 128 + ct * 4 + w) * 2 + ks)) * 512 + lane * 8);
  for (int mi = 0; mi < 4; mi++) {
    int m = mp * 4 + mi;
    float facc = 0.0f;
#pragma unroll 4
    for (int it2 = 0; it2 < 16; it2++) {
      const short* ap = qfrag + ((size_t)((bh * 128 + m * 16 + it2) * 2)) * 512 + lane * 8;
      bf16x8 a0 = *(const bf16x8*)ap;
      bf16x8 a1 = *(const bf16x8*)(ap + 512);
      f32x4 c = {0, 0, 0, 0};
      c = __builtin_amdgcn_mfma_f32_16x16x32_bf16(a0, bfr[0], c, 0, 0, 0);
      c = __builtin_amdgcn_mfma_f32_16x16x32_bf16(a1, bfr[1], c, 0, 0, 0);
#pragma unroll
      for (int r = 0; r < 4; r++) facc += __builtin_amdgcn_exp2f(c[r] * KS_);
    }
    facc += __shfl_xor(facc, 16);
    facc += __shfl_xor(facc, 32);
    if (lane < 16)
      rdg[(size_t)(bh * 8 + m) * 2048 + ct * 64 + w * 16 + lane] = -__builtin_amdgcn_logf(facc);
  }
}

// ---------- attention pass 2: p = 2^(fma(S,KS,nl)); perm-packed bf16; grid (z 8, it 16, bh 16) ----------
__global__ __launch_bounds__(256) void k_attn_out4(const short* __restrict__ qfrag, const short* __restrict__ kfrag,
                                                   const short* __restrict__ vfrag, const float* __restrict__ rdg,
                                                   short* __restrict__ ao) {
  __shared__ float red[4 * 64 * 17];
  int z = blockIdx.x, it = blockIdx.y, bh = blockIdx.z;
  int b = bh >> 3, h = bh & 7;
  int i0 = it * 16;
  int t = threadIdx.x, w = t >> 6, lane = t & 63, quad = lane >> 4, l16 = lane & 15;
  const float* rb = rdg + (size_t)bh * 16384;
  bf16x8 qf[2][2];
#pragma unroll
  for (int mm = 0; mm < 2; mm++)
#pragma unroll
    for (int ks = 0; ks < 2; ks++)
      qf[mm][ks] = *(const bf16x8*)(qfrag + ((size_t)((bh * 128 + (2 * w + mm) * 16 + it) * 2 + ks)) * 512 + lane * 8);
  f32x4 acc[4] = {{0,0,0,0},{0,0,0,0},{0,0,0,0},{0,0,0,0}};
  for (int jc = 0; jc < 8; jc++) {
    bf16x8 vf[4][2];
#pragma unroll
    for (int dt = 0; dt < 4; dt++)
#pragma unroll
      for (int jf = 0; jf < 2; jf++)
        vf[dt][jf] = *(const bf16x8*)(vfrag + ((((size_t)(bh * 8 + jc) * 4 + w) * 4 + dt) * 2 + jf) * 512 + lane * 8);
    f32x4 c[2][2] = {{{0,0,0,0},{0,0,0,0}},{{0,0,0,0},{0,0,0,0}}};
#pragma unroll
    for (int jf = 0; jf < 2; jf++) {
      const short* kp = kfrag + ((size_t)((bh * 128 + z * 16 + jc * 2 + jf) * 2)) * 512 + lane * 8;
      bf16x8 k0 = *(const bf16x8*)kp;
      bf16x8 k1 = *(const bf16x8*)(kp + 512);
#pragma unroll
      for (int mm = 0; mm < 2; mm++) {
        c[jf][mm] = __builtin_amdgcn_mfma_f32_16x16x32_bf16(k0, qf[mm][0], c[jf][mm], 0, 0, 0);
        c[jf][mm] = __builtin_amdgcn_mfma_f32_16x16x32_bf16(k1, qf[mm][1], c[jf][mm], 0, 0, 0);
      }
    }
    bf16x8 pf[2];
#pragma unroll
    for (int jf = 0; jf < 2; jf++) {
      float4 nv0 = *(const float4*)(rb + (size_t)(2 * w) * 2048 + z * 256 + jc * 32 + jf * 16 + quad * 4);
      float4 nv1 = *(const float4*)(rb + (size_t)(2 * w + 1) * 2048 + z * 256 + jc * 32 + jf * 16 + quad * 4);
      float n0[4] = {nv0.x, nv0.y, nv0.z, nv0.w};
      float n1[4] = {nv1.x, nv1.y, nv1.z, nv1.w};
      unsigned u[8];
#pragma unroll
      for (int e = 0; e < 4; e++) {
        u[e]     = __builtin_bit_cast(unsigned, __builtin_amdgcn_exp2f(fmaf(c[jf][0][e], KS_, n0[e]))) + 0x8000u;
        u[e + 4] = __builtin_bit_cast(unsigned, __builtin_amdgcn_exp2f(fmaf(c[jf][1][e], KS_, n1[e]))) + 0x8000u;
      }
      uint4 pv;
      pv.x = __builtin_amdgcn_perm(u[1], u[0], 0x07060302u);
      pv.y = __builtin_amdgcn_perm(u[3], u[2], 0x07060302u);
      pv.z = __builtin_amdgcn_perm(u[5], u[4], 0x07060302u);
      pv.w = __builtin_amdgcn_perm(u[7], u[6], 0x07060302u);
      pf[jf] = __builtin_bit_cast(bf16x8, pv);
    }
#pragma unroll
    for (int dt = 0; dt < 4; dt++)
#pragma unroll
      for (int jf = 0; jf < 2; jf++)
        acc[dt] = __builtin_amdgcn_mfma_f32_16x16x32_bf16(vf[dt][jf], pf[jf], acc[dt], 0, 0, 0);
  }
#pragma unroll
  for (int dt = 0; dt < 4; dt++)
#pragma unroll
    for (int r = 0; r < 4; r++)
      red[w * 1088 + (dt * 16 + quad * 4 + r) * 17 + l16] = acc[dt][r];
  __syncthreads();
  {
    int i = t >> 4, dg = t & 15;
    float s[4] = {0, 0, 0, 0};
#pragma unroll
    for (int w2 = 0; w2 < 4; w2++)
#pragma unroll
      for (int r2 = 0; r2 < 4; r2++)
        s[r2] += red[w2 * 1088 + (dg * 4 + r2) * 17 + i];
    bf16x4 ov;
#pragma unroll
    for (int r2 = 0; r2 < 4; r2++) ov[r2] = f2bf(s[r2]);
    *(bf16x4*)(ao + (size_t)((b * 256 + i0 + i) * 8 + z) * 512 + h * 64 + dg * 4) = ov;
  }
}

// ---------- fused residual(np split-K partials) + layernorm; optional bf16 copy ----------
__global__ __launch_bounds__(256) void k_ln(const float* __restrict__ X, const float* __restrict__ P, int np,
                                            const float* __restrict__ g, const float* __restrict__ be,
                                            float* __restrict__ Y, short* __restrict__ Ybf) {
  __shared__ float sm[8];
  int row = blockIdx.x, t = threadIdx.x;
  int lane = t & 63, w = t >> 6;
  size_t base = (size_t)row * 256;
  float v = X[base + t];
  for (int p = 0; p < np; p++) v += P[(size_t)p * 1048576 + base + t];
  float s = v;
  s += __shfl_xor(s, 1); s += __shfl_xor(s, 2); s += __shfl_xor(s, 4);
  s += __shfl_xor(s, 8); s += __shfl_xor(s, 16); s += __shfl_xor(s, 32);
  if (lane == 0) sm[w] = s;
  __syncthreads();
  float mu = (sm[0] + sm[1] + sm[2] + sm[3]) * (1.0f / 256.0f);
  float dv = v - mu;
  float s2 = dv * dv;
  s2 += __shfl_xor(s2, 1); s2 += __shfl_xor(s2, 2); s2 += __shfl_xor(s2, 4);
  s2 += __shfl_xor(s2, 8); s2 += __shfl_xor(s2, 16); s2 += __shfl_xor(s2, 32);
  if (lane == 0) sm[4 + w] = s2;
  __syncthreads();
  float var = (sm[4] + sm[5] + sm[6] + sm[7]) * (1.0f / 256.0f);
  float rs = rsqrtf(var + 1e-5f);
  float res = dv * rs * g[t] + be[t];
  Y[base + t] = res;
  if (Ybf) Ybf[base + t] = f2bf(res);
}

// ---------- GEGLU (float4-vectorized) -> bf16 ----------
__global__ __launch_bounds__(256) void k_geglu(const float* __restrict__ hg, short* __restrict__ gg) {
  int idx = blockIdx.x * 256 + threadIdx.x;        // 1,048,576 total
  int r = idx >> 8, c4 = (idx & 255) * 4;
  float4 a = *(const float4*)&hg[(size_t)r * 2048 + c4];
  float4 gt = *(const float4*)&hg[(size_t)r * 2048 + 1024 + c4];
  float av[4] = {a.x, a.y, a.z, a.w};
  float gv[4] = {gt.x, gt.y, gt.z, gt.w};
  bf16x4 o;
#pragma unroll
  for (int e = 0; e < 4; e++) {
    float ge = 0.5f * gv[e] * (1.0f + erff(gv[e] * 0.70710678118654752f));
    o[e] = f2bf(av[e] * ge);
  }
  *(bf16x4*)(gg + (size_t)r * 1024 + c4) = o;
}

extern "C" void kernel_launch(void* const* d_in, const int* in_sizes, int n_in,
                              void* d_out, int out_size, void* d_ws, size_t ws_size,
                              hipStream_t stream) {
  const float* x    = (const float*)d_in[0];
  const float* Wq   = (const float*)d_in[1];
  const float* Wkv  = (const float*)d_in[2];
  const float* Wout = (const float*)d_in[3];
  const float* bout = (const float*)d_in[4];
  const float* g1   = (const float*)d_in[5];
  const float* be1  = (const float*)d_in[6];
  const float* Wff1 = (const float*)d_in[7];
  const float* bff1 = (const float*)d_in[8];
  const float* Wff2 = (const float*)d_in[9];
  const float* bff2 = (const float*)d_in[10];
  const float* g2   = (const float*)d_in[11];
  const float* be2  = (const float*)d_in[12];
  float* out = (float*)d_out;
  float* w = (float*)d_ws;

  float* xt   = w;              // 1,048,576
  float* q    = w + 1048576;
  float* kv   = w + 3145728;
  float* part = w + 1048576;    // split-K partials (reuses q/kv region)
  float* hg   = w + 1048576;
  float* y    = w + 9437184;    // 1,048,576
  float* rdg  = w + 11534336;   //   262,144  now holds -log2(den)
  short* sb     = (short*)(w + 11796480);
  short* qfrag  = sb;                    // 2,097,152
  short* kfrag  = sb + 2097152;          // 2,097,152
  short* vfrag  = sb + 4194304;          // 2,097,152
  short* xt_bf  = sb + 6291456;          // 1,048,576
  short* ao_bf  = sb + 7340032;          // 2,097,152
  short* y_bf   = sb + 9437184;          // 1,048,576
  short* gg_bf  = sb + 10485760;         // 4,194,304
  short* WqT    = sb + 14680064;
  short* WkvT   = sb + 14811136;
  short* WoutT  = sb + 15073280;
  short* Wff1T  = sb + 23461888;
  short* Wff2T  = sb + 23986176;

  k_transpose<<<dim3(8, 8, 16), dim3(32, 8), 0, stream>>>(x, xt, xt_bf);
  k_wt<<<dim3(16, 8), 256, 0, stream>>>(Wq, WqT, 256, 512);
  k_wt<<<dim3(32, 8), 256, 0, stream>>>(Wkv, WkvT, 256, 1024);
  k_wt<<<dim3(64, 128), 256, 0, stream>>>(Wout, WoutT, 4096, 2048);
  k_wt<<<dim3(64, 8), 256, 0, stream>>>(Wff1, Wff1T, 256, 2048);
  k_wt<<<dim3(8, 32), 256, 0, stream>>>(Wff2, Wff2T, 1024, 256);
  k_gemm_bf<<<dim3(8, 64, 1), 256, 0, stream>>>(xt_bf, WqT, nullptr, q, 4096, 512, 256, 256);
  k_gemm_bf<<<dim3(16, 64, 1), 256, 0, stream>>>(xt_bf, WkvT, nullptr, kv, 4096, 1024, 256, 256);
  k_prep_qfrag<<<1024, 256, 0, stream>>>(q, qfrag);
  k_prep_kfrag<<<1024, 256, 0, stream>>>(kv, kfrag);
  k_prep_vfrag<<<dim3(8, 16), 256, 0, stream>>>(kv, vfrag);
  k_attn_den4<<<dim3(32, 2, 16), 256, 0, stream>>>(qfrag, kfrag, rdg);
  k_attn_out4<<<dim3(8, 16, 16), 256, 0, stream>>>(qfrag, kfrag, vfrag, rdg, ao_bf);
  k_gemm_bf<<<dim3(32, 8, 4), 256, 0, stream>>>(ao_bf, WoutT, bout, part, 512, 2048, 4096, 1024);
  k_ln<<<4096, 256, 0, stream>>>(xt, part, 4, g1, be1, y, y_bf);
  k_gemm_bf<<<dim3(32, 64, 1), 256, 0, stream>>>(y_bf, Wff1T, bff1, hg, 4096, 2048, 256, 256);
  k_geglu<<<4096, 256, 0, stream>>>(hg, gg_bf);
  k_gemm_bf<<<dim3(4, 64, 4), 256, 0, stream>>>(gg_bf, Wff2T, bff2, part, 4096, 256, 1024, 256);
  k_ln<<<4096, 256, 0, stream>>>(y, part, 4, g2, be2, out, nullptr);
}

// Round 8
// 239.310 us; speedup vs baseline: 1.9007x; 1.1071x over previous
//
#include <hip/hip_runtime.h>
#include <math.h>

#define KS_ 0.1803368801111244f   // 0.125 * log2(e)

typedef __attribute__((ext_vector_type(8))) short bf16x8;
typedef __attribute__((ext_vector_type(4))) short bf16x4;
typedef __attribute__((ext_vector_type(4))) float f32x4;

__device__ inline short f2bf(float f) {
  unsigned u = __builtin_bit_cast(unsigned, f);
  u += 0x7fff + ((u >> 16) & 1);
  return (short)(u >> 16);
}

// ---------- transpose x [B,D,M,N] -> xt [B,N,M,D] fp32 + bf16 ----------
__global__ __launch_bounds__(256) void k_transpose(const float* __restrict__ x, float* __restrict__ xt,
                                                   short* __restrict__ xtbf) {
  __shared__ float tile[32][33];
  int bm = blockIdx.z; int b = bm >> 3; int m = bm & 7;
  int d0 = blockIdx.x * 32, n0 = blockIdx.y * 32;
#pragma unroll
  for (int r = 0; r < 32; r += 8) {
    int d = d0 + threadIdx.y + r, n = n0 + threadIdx.x;
    tile[threadIdx.y + r][threadIdx.x] = x[((size_t)(b * 256 + d) * 8 + m) * 256 + n];
  }
  __syncthreads();
#pragma unroll
  for (int r = 0; r < 32; r += 8) {
    int n = n0 + threadIdx.y + r, d = d0 + threadIdx.x;
    float v = tile[threadIdx.x][threadIdx.y + r];
    size_t idx = ((size_t)(b * 256 + n) * 8 + m) * 256 + d;
    xt[idx] = v;
    xtbf[idx] = f2bf(v);
  }
}

// ---------- weight transpose+convert: W fp32 [K][N] -> WT bf16 [N][K] ----------
__global__ __launch_bounds__(256) void k_wt(const float* __restrict__ W, short* __restrict__ WT, int K, int N) {
  __shared__ float tile[32][33];
  int n0 = blockIdx.x * 32, k0 = blockIdx.y * 32;
  int tx = threadIdx.x & 31, ty = threadIdx.x >> 5;
#pragma unroll
  for (int r = 0; r < 32; r += 8)
    tile[ty + r][tx] = W[(size_t)(k0 + ty + r) * N + n0 + tx];
  __syncthreads();
#pragma unroll
  for (int r = 0; r < 32; r += 8)
    WT[(size_t)(n0 + ty + r) * K + k0 + tx] = f2bf(tile[tx][ty + r]);
}

// ---------- bf16 MFMA GEMM with split-K + register-prefetch pipeline ----------
__global__ __launch_bounds__(256) void k_gemm_bf(const short* __restrict__ A, const short* __restrict__ Bt,
                                                 const float* __restrict__ bias, float* __restrict__ C,
                                                 int M, int N, int K, int Ks) {
  __shared__ short As[64 * 40];
  __shared__ short Bs[64 * 40];
  int t = threadIdx.x;
  int row0 = blockIdx.y * 64, col0 = blockIdx.x * 64;
  int kp = blockIdx.z;
  int kbeg = kp * Ks, kend = kbeg + Ks;
  int w = t >> 6, lane = t & 63, quad = lane >> 4, l16 = lane & 15;
  int wr = w >> 1, wc = w & 1;
  int lrow = t >> 2, lch = (t & 3) * 8;
  const short* Ap = A + (size_t)(row0 + lrow) * K + lch;
  const short* Bp = Bt + (size_t)(col0 + lrow) * K + lch;
  f32x4 acc[2][2] = {{{0,0,0,0},{0,0,0,0}},{{0,0,0,0},{0,0,0,0}}};
  bf16x8 av = *(const bf16x8*)(Ap + kbeg);
  bf16x8 bv = *(const bf16x8*)(Bp + kbeg);
  for (int k0 = kbeg; k0 < kend; k0 += 32) {
    *(bf16x8*)&As[lrow * 40 + lch] = av;
    *(bf16x8*)&Bs[lrow * 40 + lch] = bv;
    __syncthreads();
    if (k0 + 32 < kend) {
      av = *(const bf16x8*)(Ap + k0 + 32);
      bv = *(const bf16x8*)(Bp + k0 + 32);
    }
    bf16x8 af[2], bf[2];
#pragma unroll
    for (int rf = 0; rf < 2; rf++) af[rf] = *(const bf16x8*)&As[(wr * 32 + rf * 16 + l16) * 40 + quad * 8];
#pragma unroll
    for (int cf = 0; cf < 2; cf++) bf[cf] = *(const bf16x8*)&Bs[(wc * 32 + cf * 16 + l16) * 40 + quad * 8];
#pragma unroll
    for (int rf = 0; rf < 2; rf++)
#pragma unroll
      for (int cf = 0; cf < 2; cf++)
        acc[rf][cf] = __builtin_amdgcn_mfma_f32_16x16x32_bf16(af[rf], bf[cf], acc[rf][cf], 0, 0, 0);
    __syncthreads();
  }
  float* Cp = C + (size_t)kp * M * N;
#pragma unroll
  for (int rf = 0; rf < 2; rf++)
#pragma unroll
    for (int cf = 0; cf < 2; cf++) {
      int col = col0 + wc * 32 + cf * 16 + l16;
      float vb = (bias && kp == 0) ? bias[col] : 0.0f;
#pragma unroll
      for (int r = 0; r < 4; r++) {
        int row = row0 + wr * 32 + rf * 16 + quad * 4 + r;
        Cp[(size_t)row * N + col] = acc[rf][cf][r] + vb;
      }
    }
}

// ---------- fused ff1 GEMM + GEGLU: gg = (y@Wff1+b)[:,0:1024] * gelu((...)[:,1024:2048]) ----------
__global__ __launch_bounds__(256) void k_ff1g(const short* __restrict__ A, const short* __restrict__ Bt,
                                              const float* __restrict__ bias, short* __restrict__ gg) {
  __shared__ short As[64 * 40];
  __shared__ short Ba[64 * 40];
  __shared__ short Bg[64 * 40];
  int t = threadIdx.x;
  int colA0 = blockIdx.x * 64, row0 = blockIdx.y * 64;
  int w = t >> 6, lane = t & 63, quad = lane >> 4, l16 = lane & 15;
  int wr = w >> 1, wc = w & 1;
  int lrow = t >> 2, lch = (t & 3) * 8;
  const short* Ap  = A + (size_t)(row0 + lrow) * 256 + lch;
  const short* Bpa = Bt + (size_t)(colA0 + lrow) * 256 + lch;
  const short* Bpg = Bt + (size_t)(1024 + colA0 + lrow) * 256 + lch;
  f32x4 za = {0, 0, 0, 0};
  f32x4 acc_a[2][2] = {{za, za}, {za, za}};
  f32x4 acc_g[2][2] = {{za, za}, {za, za}};
  bf16x8 av = *(const bf16x8*)(Ap);
  bf16x8 bva = *(const bf16x8*)(Bpa);
  bf16x8 bvg = *(const bf16x8*)(Bpg);
  for (int k0 = 0; k0 < 256; k0 += 32) {
    *(bf16x8*)&As[lrow * 40 + lch] = av;
    *(bf16x8*)&Ba[lrow * 40 + lch] = bva;
    *(bf16x8*)&Bg[lrow * 40 + lch] = bvg;
    __syncthreads();
    if (k0 + 32 < 256) {
      av  = *(const bf16x8*)(Ap + k0 + 32);
      bva = *(const bf16x8*)(Bpa + k0 + 32);
      bvg = *(const bf16x8*)(Bpg + k0 + 32);
    }
    bf16x8 af[2], ba[2], bg[2];
#pragma unroll
    for (int rf = 0; rf < 2; rf++) af[rf] = *(const bf16x8*)&As[(wr * 32 + rf * 16 + l16) * 40 + quad * 8];
#pragma unroll
    for (int cf = 0; cf < 2; cf++) {
      ba[cf] = *(const bf16x8*)&Ba[(wc * 32 + cf * 16 + l16) * 40 + quad * 8];
      bg[cf] = *(const bf16x8*)&Bg[(wc * 32 + cf * 16 + l16) * 40 + quad * 8];
    }
#pragma unroll
    for (int rf = 0; rf < 2; rf++)
#pragma unroll
      for (int cf = 0; cf < 2; cf++) {
        acc_a[rf][cf] = __builtin_amdgcn_mfma_f32_16x16x32_bf16(af[rf], ba[cf], acc_a[rf][cf], 0, 0, 0);
        acc_g[rf][cf] = __builtin_amdgcn_mfma_f32_16x16x32_bf16(af[rf], bg[cf], acc_g[rf][cf], 0, 0, 0);
      }
    __syncthreads();
  }
#pragma unroll
  for (int rf = 0; rf < 2; rf++)
#pragma unroll
    for (int cf = 0; cf < 2; cf++) {
      int col = colA0 + wc * 32 + cf * 16 + l16;
      float ba_ = bias[col], bg_ = bias[1024 + col];
#pragma unroll
      for (int r = 0; r < 4; r++) {
        int row = row0 + wr * 32 + rf * 16 + quad * 4 + r;
        float a = acc_a[rf][cf][r] + ba_;
        float g = acc_g[rf][cf][r] + bg_;
        float ge = 0.5f * g * (1.0f + erff(g * 0.70710678118654752f));
        gg[(size_t)row * 1024 + col] = f2bf(a * ge);
      }
    }
}

// ---------- prep: qkv fp32 [4096,1536] -> qfrag[bh][rt=(m*16+it)][ks][lane][8] ----------
__global__ __launch_bounds__(256) void k_prep_qfrag(const float* __restrict__ qkv, short* __restrict__ qfrag) {
  int c = blockIdx.x * 256 + threadIdx.x;
  int lane = c & 63, ks = (c >> 6) & 1, rt = (c >> 7) & 127, bh = c >> 14;
  int b = bh >> 3, h = bh & 7;
  int m = rt >> 4, i = ((rt & 15) << 4) + (lane & 15);
  int d = ks * 32 + (lane >> 4) * 8;
  const float* src = qkv + (size_t)((b * 256 + i) * 8 + m) * 1536 + h * 64 + d;
  float4 f0 = *(const float4*)src, f1 = *(const float4*)(src + 4);
  bf16x8 o;
  o[0] = f2bf(f0.x); o[1] = f2bf(f0.y); o[2] = f2bf(f0.z); o[3] = f2bf(f0.w);
  o[4] = f2bf(f1.x); o[5] = f2bf(f1.y); o[6] = f2bf(f1.z); o[7] = f2bf(f1.w);
  *(bf16x8*)(qfrag + (size_t)c * 8) = o;
}

// ---------- prep: qkv k-part -> kfrag[bh][rt=(z*16+jt)][ks][lane][8] ----------
__global__ __launch_bounds__(256) void k_prep_kfrag(const float* __restrict__ qkv, short* __restrict__ kfrag) {
  int c = blockIdx.x * 256 + threadIdx.x;
  int lane = c & 63, ks = (c >> 6) & 1, rt = (c >> 7) & 127, bh = c >> 14;
  int b = bh >> 3, h = bh & 7;
  int z = rt >> 4, j = ((rt & 15) << 4) + (lane & 15);
  int d = ks * 32 + (lane >> 4) * 8;
  const float* src = qkv + (size_t)((b * 256 + j) * 8 + z) * 1536 + 512 + h * 64 + d;
  float4 f0 = *(const float4*)src, f1 = *(const float4*)(src + 4);
  bf16x8 o;
  o[0] = f2bf(f0.x); o[1] = f2bf(f0.y); o[2] = f2bf(f0.z); o[3] = f2bf(f0.w);
  o[4] = f2bf(f1.x); o[5] = f2bf(f1.y); o[6] = f2bf(f1.z); o[7] = f2bf(f1.w);
  *(bf16x8*)(kfrag + (size_t)c * 8) = o;
}

// ---------- prep: qkv v-part -> vfrag[bh][jc][m0][dt][jf][lane][8] ----------
__global__ __launch_bounds__(256) void k_prep_vfrag(const float* __restrict__ qkv, short* __restrict__ vfrag) {
  __shared__ float Vs[256 * 66];
  int jc = blockIdx.x, bh = blockIdx.y;
  int b = bh >> 3, h = bh & 7;
  int t = threadIdx.x;
#pragma unroll
  for (int cc = 0; cc < 16; cc++) {
    int c = cc * 256 + t;
    int row = c >> 4, ch = c & 15;
    int m = row >> 5, jl = row & 31;
    float4 f = *(const float4*)(qkv + (size_t)((b * 256 + jc * 32 + jl) * 8 + m) * 1536 + 1024 + h * 64 + ch * 4);
    *(float4*)&Vs[row * 66 + ch * 4] = f;
  }
  __syncthreads();
  int m0 = t >> 6, lane = t & 63, quad = lane >> 4, l16 = lane & 15;
#pragma unroll
  for (int dt = 0; dt < 4; dt++)
#pragma unroll
    for (int jf = 0; jf < 2; jf++) {
      bf16x8 o;
#pragma unroll
      for (int e = 0; e < 8; e++) {
        int row = (2 * m0 + (e >> 2)) * 32 + jf * 16 + quad * 4 + (e & 3);
        o[e] = f2bf(Vs[row * 66 + dt * 16 + l16]);
      }
      size_t cid = ((((size_t)(bh * 8 + jc) * 4 + m0) * 4 + dt) * 2 + jf) * 64 + lane;
      *(bf16x8*)(vfrag + cid * 8) = o;
    }
}

// ---------- attention pass 1: 2 K-frags per wave; grid (ct2 16, mp 4, bh 16) ----------
__global__ __launch_bounds__(256) void k_attn_den5(const short* __restrict__ qfrag, const short* __restrict__ kfrag,
                                                   float* __restrict__ rdg) {
  int ct2 = blockIdx.x, mp = blockIdx.y, bh = blockIdx.z;
  int t = threadIdx.x;
  int w = t >> 6, lane = t & 63;
  int rt0 = ct2 * 8 + w * 2;
  bf16x8 bfr[2][2];
#pragma unroll
  for (int cf = 0; cf < 2; cf++)
#pragma unroll
    for (int ks = 0; ks < 2; ks++)
      bfr[cf][ks] = *(const bf16x8*)(kfrag + ((size_t)((bh * 128 + rt0 + cf) * 2 + ks)) * 512 + lane * 8);
  for (int mi = 0; mi < 2; mi++) {
    int m = mp * 2 + mi;
    float fa0 = 0.0f, fa1 = 0.0f;
#pragma unroll 4
    for (int it2 = 0; it2 < 16; it2++) {
      const short* ap = qfrag + ((size_t)((bh * 128 + m * 16 + it2) * 2)) * 512 + lane * 8;
      bf16x8 a0 = *(const bf16x8*)ap;
      bf16x8 a1 = *(const bf16x8*)(ap + 512);
      f32x4 c0 = {0, 0, 0, 0}, c1 = {0, 0, 0, 0};
      c0 = __builtin_amdgcn_mfma_f32_16x16x32_bf16(a0, bfr[0][0], c0, 0, 0, 0);
      c0 = __builtin_amdgcn_mfma_f32_16x16x32_bf16(a1, bfr[0][1], c0, 0, 0, 0);
      c1 = __builtin_amdgcn_mfma_f32_16x16x32_bf16(a0, bfr[1][0], c1, 0, 0, 0);
      c1 = __builtin_amdgcn_mfma_f32_16x16x32_bf16(a1, bfr[1][1], c1, 0, 0, 0);
#pragma unroll
      for (int r = 0; r < 4; r++) {
        fa0 += __builtin_amdgcn_exp2f(c0[r] * KS_);
        fa1 += __builtin_amdgcn_exp2f(c1[r] * KS_);
      }
    }
    fa0 += __shfl_xor(fa0, 16); fa0 += __shfl_xor(fa0, 32);
    fa1 += __shfl_xor(fa1, 16); fa1 += __shfl_xor(fa1, 32);
    if (lane < 16) {
      rdg[(size_t)(bh * 8 + m) * 2048 + rt0 * 16 + lane] = -__builtin_amdgcn_logf(fa0);
      rdg[(size_t)(bh * 8 + m) * 2048 + (rt0 + 1) * 16 + lane] = -__builtin_amdgcn_logf(fa1);
    }
  }
}

// ---------- attention pass 2: 2 i-tiles per block; grid (z 8, itp 8, bh 16) ----------
__global__ __launch_bounds__(256) void k_attn_out5(const short* __restrict__ qfrag, const short* __restrict__ kfrag,
                                                   const short* __restrict__ vfrag, const float* __restrict__ rdg,
                                                   short* __restrict__ ao) {
  __shared__ float red[4 * 64 * 17];
  int z = blockIdx.x, itp = blockIdx.y, bh = blockIdx.z;
  int b = bh >> 3, h = bh & 7;
  int t = threadIdx.x, w = t >> 6, lane = t & 63, quad = lane >> 4, l16 = lane & 15;
  const float* rb = rdg + (size_t)bh * 16384;
  f32x4 z4 = {0, 0, 0, 0};
  bf16x8 qf[2][2][2];
#pragma unroll
  for (int iti = 0; iti < 2; iti++)
#pragma unroll
    for (int mm = 0; mm < 2; mm++)
#pragma unroll
      for (int ks = 0; ks < 2; ks++)
        qf[iti][mm][ks] = *(const bf16x8*)(qfrag +
            ((size_t)((bh * 128 + (2 * w + mm) * 16 + itp * 2 + iti) * 2 + ks)) * 512 + lane * 8);
  f32x4 acc[2][4];
#pragma unroll
  for (int iti = 0; iti < 2; iti++)
#pragma unroll
    for (int dt = 0; dt < 4; dt++) acc[iti][dt] = z4;
  for (int jc = 0; jc < 8; jc++) {
    bf16x8 vf[4][2];
#pragma unroll
    for (int dt = 0; dt < 4; dt++)
#pragma unroll
      for (int jf = 0; jf < 2; jf++)
        vf[dt][jf] = *(const bf16x8*)(vfrag + ((((size_t)(bh * 8 + jc) * 4 + w) * 4 + dt) * 2 + jf) * 512 + lane * 8);
    bf16x8 kf[2][2];
#pragma unroll
    for (int jf = 0; jf < 2; jf++) {
      const short* kp = kfrag + ((size_t)((bh * 128 + z * 16 + jc * 2 + jf) * 2)) * 512 + lane * 8;
      kf[jf][0] = *(const bf16x8*)kp;
      kf[jf][1] = *(const bf16x8*)(kp + 512);
    }
    float n0[2][4], n1[2][4];
#pragma unroll
    for (int jf = 0; jf < 2; jf++) {
      float4 nv0 = *(const float4*)(rb + (size_t)(2 * w) * 2048 + z * 256 + jc * 32 + jf * 16 + quad * 4);
      float4 nv1 = *(const float4*)(rb + (size_t)(2 * w + 1) * 2048 + z * 256 + jc * 32 + jf * 16 + quad * 4);
      n0[jf][0] = nv0.x; n0[jf][1] = nv0.y; n0[jf][2] = nv0.z; n0[jf][3] = nv0.w;
      n1[jf][0] = nv1.x; n1[jf][1] = nv1.y; n1[jf][2] = nv1.z; n1[jf][3] = nv1.w;
    }
#pragma unroll
    for (int iti = 0; iti < 2; iti++) {
      f32x4 c[2][2] = {{z4, z4}, {z4, z4}};
#pragma unroll
      for (int jf = 0; jf < 2; jf++)
#pragma unroll
        for (int mm = 0; mm < 2; mm++) {
          c[jf][mm] = __builtin_amdgcn_mfma_f32_16x16x32_bf16(kf[jf][0], qf[iti][mm][0], c[jf][mm], 0, 0, 0);
          c[jf][mm] = __builtin_amdgcn_mfma_f32_16x16x32_bf16(kf[jf][1], qf[iti][mm][1], c[jf][mm], 0, 0, 0);
        }
      bf16x8 pf[2];
#pragma unroll
      for (int jf = 0; jf < 2; jf++) {
        unsigned u[8];
#pragma unroll
        for (int e = 0; e < 4; e++) {
          u[e]     = __builtin_bit_cast(unsigned, __builtin_amdgcn_exp2f(fmaf(c[jf][0][e], KS_, n0[jf][e]))) + 0x8000u;
          u[e + 4] = __builtin_bit_cast(unsigned, __builtin_amdgcn_exp2f(fmaf(c[jf][1][e], KS_, n1[jf][e]))) + 0x8000u;
        }
        uint4 pv;
        pv.x = __builtin_amdgcn_perm(u[1], u[0], 0x07060302u);
        pv.y = __builtin_amdgcn_perm(u[3], u[2], 0x07060302u);
        pv.z = __builtin_amdgcn_perm(u[5], u[4], 0x07060302u);
        pv.w = __builtin_amdgcn_perm(u[7], u[6], 0x07060302u);
        pf[jf] = __builtin_bit_cast(bf16x8, pv);
      }
#pragma unroll
      for (int dt = 0; dt < 4; dt++)
#pragma unroll
        for (int jf = 0; jf < 2; jf++)
          acc[iti][dt] = __builtin_amdgcn_mfma_f32_16x16x32_bf16(vf[dt][jf], pf[jf], acc[iti][dt], 0, 0, 0);
    }
  }
  for (int iti = 0; iti < 2; iti++) {
#pragma unroll
    for (int dt = 0; dt < 4; dt++)
#pragma unroll
      for (int r = 0; r < 4; r++)
        red[w * 1088 + (dt * 16 + quad * 4 + r) * 17 + l16] = acc[iti][dt][r];
    __syncthreads();
    {
      int i = t >> 4, dg = t & 15;
      float s[4] = {0, 0, 0, 0};
#pragma unroll
      for (int w2 = 0; w2 < 4; w2++)
#pragma unroll
        for (int r2 = 0; r2 < 4; r2++)
          s[r2] += red[w2 * 1088 + (dg * 4 + r2) * 17 + i];
      bf16x4 ov;
#pragma unroll
      for (int r2 = 0; r2 < 4; r2++) ov[r2] = f2bf(s[r2]);
      *(bf16x4*)(ao + (size_t)((b * 256 + itp * 32 + iti * 16 + i) * 8 + z) * 512 + h * 64 + dg * 4) = ov;
    }
    __syncthreads();
  }
}

// ---------- fused residual(np split-K partials) + layernorm; optional bf16 copy ----------
__global__ __launch_bounds__(256) void k_ln(const float* __restrict__ X, const float* __restrict__ P, int np,
                                            const float* __restrict__ g, const float* __restrict__ be,
                                            float* __restrict__ Y, short* __restrict__ Ybf) {
  __shared__ float sm[8];
  int row = blockIdx.x, t = threadIdx.x;
  int lane = t & 63, w = t >> 6;
  size_t base = (size_t)row * 256;
  float v = X[base + t];
  for (int p = 0; p < np; p++) v += P[(size_t)p * 1048576 + base + t];
  float s = v;
  s += __shfl_xor(s, 1); s += __shfl_xor(s, 2); s += __shfl_xor(s, 4);
  s += __shfl_xor(s, 8); s += __shfl_xor(s, 16); s += __shfl_xor(s, 32);
  if (lane == 0) sm[w] = s;
  __syncthreads();
  float mu = (sm[0] + sm[1] + sm[2] + sm[3]) * (1.0f / 256.0f);
  float dv = v - mu;
  float s2 = dv * dv;
  s2 += __shfl_xor(s2, 1); s2 += __shfl_xor(s2, 2); s2 += __shfl_xor(s2, 4);
  s2 += __shfl_xor(s2, 8); s2 += __shfl_xor(s2, 16); s2 += __shfl_xor(s2, 32);
  if (lane == 0) sm[4 + w] = s2;
  __syncthreads();
  float var = (sm[4] + sm[5] + sm[6] + sm[7]) * (1.0f / 256.0f);
  float rs = rsqrtf(var + 1e-5f);
  float res = dv * rs * g[t] + be[t];
  Y[base + t] = res;
  if (Ybf) Ybf[base + t] = f2bf(res);
}

extern "C" void kernel_launch(void* const* d_in, const int* in_sizes, int n_in,
                              void* d_out, int out_size, void* d_ws, size_t ws_size,
                              hipStream_t stream) {
  const float* x    = (const float*)d_in[0];
  const float* Wq   = (const float*)d_in[1];
  const float* Wkv  = (const float*)d_in[2];
  const float* Wout = (const float*)d_in[3];
  const float* bout = (const float*)d_in[4];
  const float* g1   = (const float*)d_in[5];
  const float* be1  = (const float*)d_in[6];
  const float* Wff1 = (const float*)d_in[7];
  const float* bff1 = (const float*)d_in[8];
  const float* Wff2 = (const float*)d_in[9];
  const float* bff2 = (const float*)d_in[10];
  const float* g2   = (const float*)d_in[11];
  const float* be2  = (const float*)d_in[12];
  float* out = (float*)d_out;
  float* w = (float*)d_ws;

  // fp32 zone; region w+1048576.. is time-multiplexed: qkv (6.3M) -> Wout partials (4M) -> ff2 partials (4M)
  float* xt   = w;              // 1,048,576
  float* qkv  = w + 1048576;    // 6,291,456  [4096][1536] = q|k|v
  float* part = w + 1048576;    // split-K partials (qkv dead by then)
  float* y    = w + 9437184;    // 1,048,576
  float* rdg  = w + 11534336;   //   262,144  -log2(den), [bh*8+m][2048]
  // bf16 zone
  short* sb     = (short*)(w + 11796480);
  short* qfrag  = sb;                    // 2,097,152
  short* kfrag  = sb + 2097152;          // 2,097,152
  short* vfrag  = sb + 4194304;          // 2,097,152
  short* xt_bf  = sb + 6291456;          // 1,048,576
  short* ao_bf  = sb + 7340032;          // 2,097,152
  short* y_bf   = sb + 9437184;          // 1,048,576
  short* gg_bf  = sb + 10485760;         // 4,194,304
  short* WqkvT  = sb + 14680064;         //   393,216  [1536][256] (Wq rows 0..511, Wkv rows 512..1535)
  short* WoutT  = sb + 15073280;         // 8,388,608
  short* Wff1T  = sb + 23461888;         //   524,288
  short* Wff2T  = sb + 23986176;         //   262,144

  k_transpose<<<dim3(8, 8, 16), dim3(32, 8), 0, stream>>>(x, xt, xt_bf);
  k_wt<<<dim3(16, 8), 256, 0, stream>>>(Wq, WqkvT, 256, 512);
  k_wt<<<dim3(32, 8), 256, 0, stream>>>(Wkv, WqkvT + 131072, 256, 1024);
  k_wt<<<dim3(64, 128), 256, 0, stream>>>(Wout, WoutT, 4096, 2048);
  k_wt<<<dim3(64, 8), 256, 0, stream>>>(Wff1, Wff1T, 256, 2048);
  k_wt<<<dim3(8, 32), 256, 0, stream>>>(Wff2, Wff2T, 1024, 256);
  k_gemm_bf<<<dim3(24, 64, 1), 256, 0, stream>>>(xt_bf, WqkvT, nullptr, qkv, 4096, 1536, 256, 256);
  k_prep_qfrag<<<1024, 256, 0, stream>>>(qkv, qfrag);
  k_prep_kfrag<<<1024, 256, 0, stream>>>(qkv, kfrag);
  k_prep_vfrag<<<dim3(8, 16), 256, 0, stream>>>(qkv, vfrag);
  k_attn_den5<<<dim3(16, 4, 16), 256, 0, stream>>>(qfrag, kfrag, rdg);
  k_attn_out5<<<dim3(8, 8, 16), 256, 0, stream>>>(qfrag, kfrag, vfrag, rdg, ao_bf);
  k_gemm_bf<<<dim3(32, 8, 4), 256, 0, stream>>>(ao_bf, WoutT, bout, part, 512, 2048, 4096, 1024);
  k_ln<<<4096, 256, 0, stream>>>(xt, part, 4, g1, be1, y, y_bf);
  k_ff1g<<<dim3(16, 64), 256, 0, stream>>>(y_bf, Wff1T, bff1, gg_bf);
  k_gemm_bf<<<dim3(4, 64, 4), 256, 0, stream>>>(gg_bf, Wff2T, bff2, part, 4096, 256, 1024, 256);
  k_ln<<<4096, 256, 0, stream>>>(y, part, 4, g2, be2, out, nullptr);
}

// Round 9
// 230.870 us; speedup vs baseline: 1.9702x; 1.0366x over previous
//
#include <hip/hip_runtime.h>
#include <math.h>

#define KS_ 0.1803368801111244f   // 0.125 * log2(e)

typedef __attribute__((ext_vector_type(8))) short bf16x8;
typedef __attribute__((ext_vector_type(4))) short bf16x4;
typedef __attribute__((ext_vector_type(4))) float f32x4;

__device__ inline short f2bf(float f) {
  unsigned u = __builtin_bit_cast(unsigned, f);
  u += 0x7fff + ((u >> 16) & 1);
  return (short)(u >> 16);
}

// ---------- helper: 32x32 transpose tile of W [K][N] -> WT bf16 [N][K] ----------
__device__ inline void wt_tile(const float* __restrict__ W, short* __restrict__ WT,
                               int K, int N, int bx, int by, int t, float (*tile)[33]) {
  int n0 = bx * 32, k0 = by * 32;
  int tx = t & 31, ty = t >> 5;
#pragma unroll
  for (int r = 0; r < 32; r += 8)
    tile[ty + r][tx] = W[(size_t)(k0 + ty + r) * N + n0 + tx];
  __syncthreads();
#pragma unroll
  for (int r = 0; r < 32; r += 8)
    WT[(size_t)(n0 + ty + r) * K + k0 + tx] = f2bf(tile[tx][ty + r]);
}

// ---------- mega prep: x-transpose + all 5 weight transposes in one launch ----------
// grid 10368: [0,8192) Wout | [8192,9216) x-transpose | then Wq 128 | Wkv 256 | Wff1 512 | Wff2 256
__global__ __launch_bounds__(256) void k_prep_all(const float* __restrict__ x, float* __restrict__ xt,
                                                  short* __restrict__ xtbf,
                                                  const float* __restrict__ Wq, const float* __restrict__ Wkv,
                                                  const float* __restrict__ Wout, const float* __restrict__ Wff1,
                                                  const float* __restrict__ Wff2,
                                                  short* __restrict__ WqkvT, short* __restrict__ WoutT,
                                                  short* __restrict__ Wff1T, short* __restrict__ Wff2T) {
  __shared__ float tile[32][33];
  int bid = blockIdx.x, t = threadIdx.x;
  if (bid < 8192) {
    wt_tile(Wout, WoutT, 4096, 2048, bid & 63, bid >> 6, t, tile);
  } else if (bid < 9216) {
    int r = bid - 8192;
    int bx = r & 7, by = (r >> 3) & 7, bm = r >> 6;
    int b = bm >> 3, m = bm & 7;
    int d0 = bx * 32, n0 = by * 32;
    int tx = t & 31, ty = t >> 5;
#pragma unroll
    for (int rr = 0; rr < 32; rr += 8) {
      int d = d0 + ty + rr, n = n0 + tx;
      tile[ty + rr][tx] = x[((size_t)(b * 256 + d) * 8 + m) * 256 + n];
    }
    __syncthreads();
#pragma unroll
    for (int rr = 0; rr < 32; rr += 8) {
      int n = n0 + ty + rr, d = d0 + tx;
      float v = tile[tx][ty + rr];
      size_t idx = ((size_t)(b * 256 + n) * 8 + m) * 256 + d;
      xt[idx] = v;
      xtbf[idx] = f2bf(v);
    }
  } else if (bid < 9344) {
    int r = bid - 9216;
    wt_tile(Wq, WqkvT, 256, 512, r & 15, r >> 4, t, tile);
  } else if (bid < 9600) {
    int r = bid - 9344;
    wt_tile(Wkv, WqkvT + 131072, 256, 1024, r & 31, r >> 5, t, tile);
  } else if (bid < 10112) {
    int r = bid - 9600;
    wt_tile(Wff1, Wff1T, 256, 2048, r & 63, r >> 6, t, tile);
  } else {
    int r = bid - 10112;
    wt_tile(Wff2, Wff2T, 1024, 256, r & 7, r >> 3, t, tile);
  }
}

// ---------- bf16 MFMA GEMM with split-K + register-prefetch pipeline ----------
__global__ __launch_bounds__(256) void k_gemm_bf(const short* __restrict__ A, const short* __restrict__ Bt,
                                                 const float* __restrict__ bias, float* __restrict__ C,
                                                 int M, int N, int K, int Ks) {
  __shared__ short As[64 * 40];
  __shared__ short Bs[64 * 40];
  int t = threadIdx.x;
  int row0 = blockIdx.y * 64, col0 = blockIdx.x * 64;
  int kp = blockIdx.z;
  int kbeg = kp * Ks, kend = kbeg + Ks;
  int w = t >> 6, lane = t & 63, quad = lane >> 4, l16 = lane & 15;
  int wr = w >> 1, wc = w & 1;
  int lrow = t >> 2, lch = (t & 3) * 8;
  const short* Ap = A + (size_t)(row0 + lrow) * K + lch;
  const short* Bp = Bt + (size_t)(col0 + lrow) * K + lch;
  f32x4 acc[2][2] = {{{0,0,0,0},{0,0,0,0}},{{0,0,0,0},{0,0,0,0}}};
  bf16x8 av = *(const bf16x8*)(Ap + kbeg);
  bf16x8 bv = *(const bf16x8*)(Bp + kbeg);
  for (int k0 = kbeg; k0 < kend; k0 += 32) {
    *(bf16x8*)&As[lrow * 40 + lch] = av;
    *(bf16x8*)&Bs[lrow * 40 + lch] = bv;
    __syncthreads();
    if (k0 + 32 < kend) {
      av = *(const bf16x8*)(Ap + k0 + 32);
      bv = *(const bf16x8*)(Bp + k0 + 32);
    }
    bf16x8 af[2], bf[2];
#pragma unroll
    for (int rf = 0; rf < 2; rf++) af[rf] = *(const bf16x8*)&As[(wr * 32 + rf * 16 + l16) * 40 + quad * 8];
#pragma unroll
    for (int cf = 0; cf < 2; cf++) bf[cf] = *(const bf16x8*)&Bs[(wc * 32 + cf * 16 + l16) * 40 + quad * 8];
#pragma unroll
    for (int rf = 0; rf < 2; rf++)
#pragma unroll
      for (int cf = 0; cf < 2; cf++)
        acc[rf][cf] = __builtin_amdgcn_mfma_f32_16x16x32_bf16(af[rf], bf[cf], acc[rf][cf], 0, 0, 0);
    __syncthreads();
  }
  float* Cp = C + (size_t)kp * M * N;
#pragma unroll
  for (int rf = 0; rf < 2; rf++)
#pragma unroll
    for (int cf = 0; cf < 2; cf++) {
      int col = col0 + wc * 32 + cf * 16 + l16;
      float vb = (bias && kp == 0) ? bias[col] : 0.0f;
#pragma unroll
      for (int r = 0; r < 4; r++) {
        int row = row0 + wr * 32 + rf * 16 + quad * 4 + r;
        Cp[(size_t)row * N + col] = acc[rf][cf][r] + vb;
      }
    }
}

// ---------- fused ff1 GEMM + GEGLU ----------
__global__ __launch_bounds__(256) void k_ff1g(const short* __restrict__ A, const short* __restrict__ Bt,
                                              const float* __restrict__ bias, short* __restrict__ gg) {
  __shared__ short As[64 * 40];
  __shared__ short Ba[64 * 40];
  __shared__ short Bg[64 * 40];
  int t = threadIdx.x;
  int colA0 = blockIdx.x * 64, row0 = blockIdx.y * 64;
  int w = t >> 6, lane = t & 63, quad = lane >> 4, l16 = lane & 15;
  int wr = w >> 1, wc = w & 1;
  int lrow = t >> 2, lch = (t & 3) * 8;
  const short* Ap  = A + (size_t)(row0 + lrow) * 256 + lch;
  const short* Bpa = Bt + (size_t)(colA0 + lrow) * 256 + lch;
  const short* Bpg = Bt + (size_t)(1024 + colA0 + lrow) * 256 + lch;
  f32x4 za = {0, 0, 0, 0};
  f32x4 acc_a[2][2] = {{za, za}, {za, za}};
  f32x4 acc_g[2][2] = {{za, za}, {za, za}};
  bf16x8 av = *(const bf16x8*)(Ap);
  bf16x8 bva = *(const bf16x8*)(Bpa);
  bf16x8 bvg = *(const bf16x8*)(Bpg);
  for (int k0 = 0; k0 < 256; k0 += 32) {
    *(bf16x8*)&As[lrow * 40 + lch] = av;
    *(bf16x8*)&Ba[lrow * 40 + lch] = bva;
    *(bf16x8*)&Bg[lrow * 40 + lch] = bvg;
    __syncthreads();
    if (k0 + 32 < 256) {
      av  = *(const bf16x8*)(Ap + k0 + 32);
      bva = *(const bf16x8*)(Bpa + k0 + 32);
      bvg = *(const bf16x8*)(Bpg + k0 + 32);
    }
    bf16x8 af[2], ba[2], bg[2];
#pragma unroll
    for (int rf = 0; rf < 2; rf++) af[rf] = *(const bf16x8*)&As[(wr * 32 + rf * 16 + l16) * 40 + quad * 8];
#pragma unroll
    for (int cf = 0; cf < 2; cf++) {
      ba[cf] = *(const bf16x8*)&Ba[(wc * 32 + cf * 16 + l16) * 40 + quad * 8];
      bg[cf] = *(const bf16x8*)&Bg[(wc * 32 + cf * 16 + l16) * 40 + quad * 8];
    }
#pragma unroll
    for (int rf = 0; rf < 2; rf++)
#pragma unroll
      for (int cf = 0; cf < 2; cf++) {
        acc_a[rf][cf] = __builtin_amdgcn_mfma_f32_16x16x32_bf16(af[rf], ba[cf], acc_a[rf][cf], 0, 0, 0);
        acc_g[rf][cf] = __builtin_amdgcn_mfma_f32_16x16x32_bf16(af[rf], bg[cf], acc_g[rf][cf], 0, 0, 0);
      }
    __syncthreads();
  }
#pragma unroll
  for (int rf = 0; rf < 2; rf++)
#pragma unroll
    for (int cf = 0; cf < 2; cf++) {
      int col = colA0 + wc * 32 + cf * 16 + l16;
      float ba_ = bias[col], bg_ = bias[1024 + col];
#pragma unroll
      for (int r = 0; r < 4; r++) {
        int row = row0 + wr * 32 + rf * 16 + quad * 4 + r;
        float a = acc_a[rf][cf][r] + ba_;
        float g = acc_g[rf][cf][r] + bg_;
        float ge = 0.5f * g * (1.0f + erff(g * 0.70710678118654752f));
        gg[(size_t)row * 1024 + col] = f2bf(a * ge);
      }
    }
}

// ---------- merged prep: q-frags and k-frags (grid 2048: [0,1024) q, [1024,2048) k) ----------
__global__ __launch_bounds__(256) void k_prep_qk(const float* __restrict__ qkv, short* __restrict__ qfrag,
                                                 short* __restrict__ kfrag) {
  int bid = blockIdx.x;
  int sel = bid >> 10;                      // 0 = q, 1 = k
  int c = (bid & 1023) * 256 + threadIdx.x;
  int lane = c & 63, ks = (c >> 6) & 1, rt = (c >> 7) & 127, bh = c >> 14;
  int b = bh >> 3, h = bh & 7;
  int mz = rt >> 4, ij = ((rt & 15) << 4) + (lane & 15);
  int d = ks * 32 + (lane >> 4) * 8;
  const float* src = qkv + (size_t)((b * 256 + ij) * 8 + mz) * 1536 + sel * 512 + h * 64 + d;
  float4 f0 = *(const float4*)src, f1 = *(const float4*)(src + 4);
  bf16x8 o;
  o[0] = f2bf(f0.x); o[1] = f2bf(f0.y); o[2] = f2bf(f0.z); o[3] = f2bf(f0.w);
  o[4] = f2bf(f1.x); o[5] = f2bf(f1.y); o[6] = f2bf(f1.z); o[7] = f2bf(f1.w);
  short* dst = sel ? kfrag : qfrag;
  *(bf16x8*)(dst + (size_t)c * 8) = o;
}

// ---------- prep: qkv v-part -> vfrag[bh][jc][m0][dt][jf][lane][8] ----------
__global__ __launch_bounds__(256) void k_prep_vfrag(const float* __restrict__ qkv, short* __restrict__ vfrag) {
  __shared__ float Vs[256 * 66];
  int jc = blockIdx.x, bh = blockIdx.y;
  int b = bh >> 3, h = bh & 7;
  int t = threadIdx.x;
#pragma unroll
  for (int cc = 0; cc < 16; cc++) {
    int c = cc * 256 + t;
    int row = c >> 4, ch = c & 15;
    int m = row >> 5, jl = row & 31;
    float4 f = *(const float4*)(qkv + (size_t)((b * 256 + jc * 32 + jl) * 8 + m) * 1536 + 1024 + h * 64 + ch * 4);
    *(float4*)&Vs[row * 66 + ch * 4] = f;
  }
  __syncthreads();
  int m0 = t >> 6, lane = t & 63, quad = lane >> 4, l16 = lane & 15;
#pragma unroll
  for (int dt = 0; dt < 4; dt++)
#pragma unroll
    for (int jf = 0; jf < 2; jf++) {
      bf16x8 o;
#pragma unroll
      for (int e = 0; e < 8; e++) {
        int row = (2 * m0 + (e >> 2)) * 32 + jf * 16 + quad * 4 + (e & 3);
        o[e] = f2bf(Vs[row * 66 + dt * 16 + l16]);
      }
      size_t cid = ((((size_t)(bh * 8 + jc) * 4 + m0) * 4 + dt) * 2 + jf) * 64 + lane;
      *(bf16x8*)(vfrag + cid * 8) = o;
    }
}

// ---------- attention pass 1: 2 K-frags per wave; grid (ct2 16, mp 4, bh 16) ----------
__global__ __launch_bounds__(256) void k_attn_den5(const short* __restrict__ qfrag, const short* __restrict__ kfrag,
                                                   float* __restrict__ rdg) {
  int ct2 = blockIdx.x, mp = blockIdx.y, bh = blockIdx.z;
  int t = threadIdx.x;
  int w = t >> 6, lane = t & 63;
  int rt0 = ct2 * 8 + w * 2;
  bf16x8 bfr[2][2];
#pragma unroll
  for (int cf = 0; cf < 2; cf++)
#pragma unroll
    for (int ks = 0; ks < 2; ks++)
      bfr[cf][ks] = *(const bf16x8*)(kfrag + ((size_t)((bh * 128 + rt0 + cf) * 2 + ks)) * 512 + lane * 8);
  for (int mi = 0; mi < 2; mi++) {
    int m = mp * 2 + mi;
    float fa0 = 0.0f, fa1 = 0.0f;
#pragma unroll 4
    for (int it2 = 0; it2 < 16; it2++) {
      const short* ap = qfrag + ((size_t)((bh * 128 + m * 16 + it2) * 2)) * 512 + lane * 8;
      bf16x8 a0 = *(const bf16x8*)ap;
      bf16x8 a1 = *(const bf16x8*)(ap + 512);
      f32x4 c0 = {0, 0, 0, 0}, c1 = {0, 0, 0, 0};
      c0 = __builtin_amdgcn_mfma_f32_16x16x32_bf16(a0, bfr[0][0], c0, 0, 0, 0);
      c0 = __builtin_amdgcn_mfma_f32_16x16x32_bf16(a1, bfr[0][1], c0, 0, 0, 0);
      c1 = __builtin_amdgcn_mfma_f32_16x16x32_bf16(a0, bfr[1][0], c1, 0, 0, 0);
      c1 = __builtin_amdgcn_mfma_f32_16x16x32_bf16(a1, bfr[1][1], c1, 0, 0, 0);
#pragma unroll
      for (int r = 0; r < 4; r++) {
        fa0 += __builtin_amdgcn_exp2f(c0[r] * KS_);
        fa1 += __builtin_amdgcn_exp2f(c1[r] * KS_);
      }
    }
    fa0 += __shfl_xor(fa0, 16); fa0 += __shfl_xor(fa0, 32);
    fa1 += __shfl_xor(fa1, 16); fa1 += __shfl_xor(fa1, 32);
    if (lane < 16) {
      rdg[(size_t)(bh * 8 + m) * 2048 + rt0 * 16 + lane] = -__builtin_amdgcn_logf(fa0);
      rdg[(size_t)(bh * 8 + m) * 2048 + (rt0 + 1) * 16 + lane] = -__builtin_amdgcn_logf(fa1);
    }
  }
}

// ---------- attention pass 2: 2 i-tiles/block + next-jc register prefetch; grid (z 8, itp 8, bh 16) ----------
__global__ __launch_bounds__(256) void k_attn_out6(const short* __restrict__ qfrag, const short* __restrict__ kfrag,
                                                   const short* __restrict__ vfrag, const float* __restrict__ rdg,
                                                   short* __restrict__ ao) {
  __shared__ float red[4 * 64 * 17];
  int z = blockIdx.x, itp = blockIdx.y, bh = blockIdx.z;
  int b = bh >> 3, h = bh & 7;
  int t = threadIdx.x, w = t >> 6, lane = t & 63, quad = lane >> 4, l16 = lane & 15;
  const float* rb = rdg + (size_t)bh * 16384;
  f32x4 z4 = {0, 0, 0, 0};
  bf16x8 qf[2][2][2];
#pragma unroll
  for (int iti = 0; iti < 2; iti++)
#pragma unroll
    for (int mm = 0; mm < 2; mm++)
#pragma unroll
      for (int ks = 0; ks < 2; ks++)
        qf[iti][mm][ks] = *(const bf16x8*)(qfrag +
            ((size_t)((bh * 128 + (2 * w + mm) * 16 + itp * 2 + iti) * 2 + ks)) * 512 + lane * 8);
  f32x4 acc[2][4];
#pragma unroll
  for (int iti = 0; iti < 2; iti++)
#pragma unroll
    for (int dt = 0; dt < 4; dt++) acc[iti][dt] = z4;
  // operand registers (current + prefetch)
  bf16x8 vf[4][2], kf[2][2];
  float4 nv0[2], nv1[2];
#pragma unroll
  for (int dt = 0; dt < 4; dt++)
#pragma unroll
    for (int jf = 0; jf < 2; jf++)
      vf[dt][jf] = *(const bf16x8*)(vfrag + ((((size_t)(bh * 8 + 0) * 4 + w) * 4 + dt) * 2 + jf) * 512 + lane * 8);
#pragma unroll
  for (int jf = 0; jf < 2; jf++) {
    const short* kp = kfrag + ((size_t)((bh * 128 + z * 16 + 0 * 2 + jf) * 2)) * 512 + lane * 8;
    kf[jf][0] = *(const bf16x8*)kp;
    kf[jf][1] = *(const bf16x8*)(kp + 512);
    nv0[jf] = *(const float4*)(rb + (size_t)(2 * w) * 2048 + z * 256 + 0 * 32 + jf * 16 + quad * 4);
    nv1[jf] = *(const float4*)(rb + (size_t)(2 * w + 1) * 2048 + z * 256 + 0 * 32 + jf * 16 + quad * 4);
  }
  for (int jc = 0; jc < 8; jc++) {
    bf16x8 vfn[4][2], kfn[2][2];
    float4 nv0n[2], nv1n[2];
    if (jc < 7) {
      int jn = jc + 1;
#pragma unroll
      for (int dt = 0; dt < 4; dt++)
#pragma unroll
        for (int jf = 0; jf < 2; jf++)
          vfn[dt][jf] = *(const bf16x8*)(vfrag + ((((size_t)(bh * 8 + jn) * 4 + w) * 4 + dt) * 2 + jf) * 512 + lane * 8);
#pragma unroll
      for (int jf = 0; jf < 2; jf++) {
        const short* kp = kfrag + ((size_t)((bh * 128 + z * 16 + jn * 2 + jf) * 2)) * 512 + lane * 8;
        kfn[jf][0] = *(const bf16x8*)kp;
        kfn[jf][1] = *(const bf16x8*)(kp + 512);
        nv0n[jf] = *(const float4*)(rb + (size_t)(2 * w) * 2048 + z * 256 + jn * 32 + jf * 16 + quad * 4);
        nv1n[jf] = *(const float4*)(rb + (size_t)(2 * w + 1) * 2048 + z * 256 + jn * 32 + jf * 16 + quad * 4);
      }
    }
    float n0[2][4] = {{nv0[0].x, nv0[0].y, nv0[0].z, nv0[0].w}, {nv0[1].x, nv0[1].y, nv0[1].z, nv0[1].w}};
    float n1[2][4] = {{nv1[0].x, nv1[0].y, nv1[0].z, nv1[0].w}, {nv1[1].x, nv1[1].y, nv1[1].z, nv1[1].w}};
#pragma unroll
    for (int iti = 0; iti < 2; iti++) {
      f32x4 c[2][2] = {{z4, z4}, {z4, z4}};
#pragma unroll
      for (int jf = 0; jf < 2; jf++)
#pragma unroll
        for (int mm = 0; mm < 2; mm++) {
          c[jf][mm] = __builtin_amdgcn_mfma_f32_16x16x32_bf16(kf[jf][0], qf[iti][mm][0], c[jf][mm], 0, 0, 0);
          c[jf][mm] = __builtin_amdgcn_mfma_f32_16x16x32_bf16(kf[jf][1], qf[iti][mm][1], c[jf][mm], 0, 0, 0);
        }
      bf16x8 pf[2];
#pragma unroll
      for (int jf = 0; jf < 2; jf++) {
        unsigned u[8];
#pragma unroll
        for (int e = 0; e < 4; e++) {
          u[e]     = __builtin_bit_cast(unsigned, __builtin_amdgcn_exp2f(fmaf(c[jf][0][e], KS_, n0[jf][e]))) + 0x8000u;
          u[e + 4] = __builtin_bit_cast(unsigned, __builtin_amdgcn_exp2f(fmaf(c[jf][1][e], KS_, n1[jf][e]))) + 0x8000u;
        }
        uint4 pv;
        pv.x = __builtin_amdgcn_perm(u[1], u[0], 0x07060302u);
        pv.y = __builtin_amdgcn_perm(u[3], u[2], 0x07060302u);
        pv.z = __builtin_amdgcn_perm(u[5], u[4], 0x07060302u);
        pv.w = __builtin_amdgcn_perm(u[7], u[6], 0x07060302u);
        pf[jf] = __builtin_bit_cast(bf16x8, pv);
      }
#pragma unroll
      for (int dt = 0; dt < 4; dt++)
#pragma unroll
        for (int jf = 0; jf < 2; jf++)
          acc[iti][dt] = __builtin_amdgcn_mfma_f32_16x16x32_bf16(vf[dt][jf], pf[jf], acc[iti][dt], 0, 0, 0);
    }
    if (jc < 7) {
#pragma unroll
      for (int dt = 0; dt < 4; dt++)
#pragma unroll
        for (int jf = 0; jf < 2; jf++) vf[dt][jf] = vfn[dt][jf];
#pragma unroll
      for (int jf = 0; jf < 2; jf++) {
        kf[jf][0] = kfn[jf][0]; kf[jf][1] = kfn[jf][1];
        nv0[jf] = nv0n[jf]; nv1[jf] = nv1n[jf];
      }
    }
  }
  for (int iti = 0; iti < 2; iti++) {
#pragma unroll
    for (int dt = 0; dt < 4; dt++)
#pragma unroll
      for (int r = 0; r < 4; r++)
        red[w * 1088 + (dt * 16 + quad * 4 + r) * 17 + l16] = acc[iti][dt][r];
    __syncthreads();
    {
      int i = t >> 4, dg = t & 15;
      float s[4] = {0, 0, 0, 0};
#pragma unroll
      for (int w2 = 0; w2 < 4; w2++)
#pragma unroll
        for (int r2 = 0; r2 < 4; r2++)
          s[r2] += red[w2 * 1088 + (dg * 4 + r2) * 17 + i];
      bf16x4 ov;
#pragma unroll
      for (int r2 = 0; r2 < 4; r2++) ov[r2] = f2bf(s[r2]);
      *(bf16x4*)(ao + (size_t)((b * 256 + itp * 32 + iti * 16 + i) * 8 + z) * 512 + h * 64 + dg * 4) = ov;
    }
    __syncthreads();
  }
}

// ---------- fused residual(np split-K partials) + layernorm; optional bf16 copy ----------
__global__ __launch_bounds__(256) void k_ln(const float* __restrict__ X, const float* __restrict__ P, int np,
                                            const float* __restrict__ g, const float* __restrict__ be,
                                            float* __restrict__ Y, short* __restrict__ Ybf) {
  __shared__ float sm[8];
  int row = blockIdx.x, t = threadIdx.x;
  int lane = t & 63, w = t >> 6;
  size_t base = (size_t)row * 256;
  float v = X[base + t];
  for (int p = 0; p < np; p++) v += P[(size_t)p * 1048576 + base + t];
  float s = v;
  s += __shfl_xor(s, 1); s += __shfl_xor(s, 2); s += __shfl_xor(s, 4);
  s += __shfl_xor(s, 8); s += __shfl_xor(s, 16); s += __shfl_xor(s, 32);
  if (lane == 0) sm[w] = s;
  __syncthreads();
  float mu = (sm[0] + sm[1] + sm[2] + sm[3]) * (1.0f / 256.0f);
  float dv = v - mu;
  float s2 = dv * dv;
  s2 += __shfl_xor(s2, 1); s2 += __shfl_xor(s2, 2); s2 += __shfl_xor(s2, 4);
  s2 += __shfl_xor(s2, 8); s2 += __shfl_xor(s2, 16); s2 += __shfl_xor(s2, 32);
  if (lane == 0) sm[4 + w] = s2;
  __syncthreads();
  float var = (sm[4] + sm[5] + sm[6] + sm[7]) * (1.0f / 256.0f);
  float rs = rsqrtf(var + 1e-5f);
  float res = dv * rs * g[t] + be[t];
  Y[base + t] = res;
  if (Ybf) Ybf[base + t] = f2bf(res);
}

extern "C" void kernel_launch(void* const* d_in, const int* in_sizes, int n_in,
                              void* d_out, int out_size, void* d_ws, size_t ws_size,
                              hipStream_t stream) {
  const float* x    = (const float*)d_in[0];
  const float* Wq   = (const float*)d_in[1];
  const float* Wkv  = (const float*)d_in[2];
  const float* Wout = (const float*)d_in[3];
  const float* bout = (const float*)d_in[4];
  const float* g1   = (const float*)d_in[5];
  const float* be1  = (const float*)d_in[6];
  const float* Wff1 = (const float*)d_in[7];
  const float* bff1 = (const float*)d_in[8];
  const float* Wff2 = (const float*)d_in[9];
  const float* bff2 = (const float*)d_in[10];
  const float* g2   = (const float*)d_in[11];
  const float* be2  = (const float*)d_in[12];
  float* out = (float*)d_out;
  float* w = (float*)d_ws;

  // fp32 zone; region w+1048576.. is time-multiplexed: qkv (6.3M) -> Wout partials (4M) -> ff2 partials (4M)
  float* xt   = w;              // 1,048,576
  float* qkv  = w + 1048576;    // 6,291,456  [4096][1536] = q|k|v
  float* part = w + 1048576;    // split-K partials (qkv dead by then)
  float* y    = w + 9437184;    // 1,048,576
  float* rdg  = w + 11534336;   //   262,144  -log2(den), [bh*8+m][2048]
  // bf16 zone
  short* sb     = (short*)(w + 11796480);
  short* qfrag  = sb;                    // 2,097,152
  short* kfrag  = sb + 2097152;          // 2,097,152
  short* vfrag  = sb + 4194304;          // 2,097,152
  short* xt_bf  = sb + 6291456;          // 1,048,576
  short* ao_bf  = sb + 7340032;          // 2,097,152
  short* y_bf   = sb + 9437184;          // 1,048,576
  short* gg_bf  = sb + 10485760;         // 4,194,304
  short* WqkvT  = sb + 14680064;         //   393,216  [1536][256]
  short* WoutT  = sb + 15073280;         // 8,388,608
  short* Wff1T  = sb + 23461888;         //   524,288
  short* Wff2T  = sb + 23986176;         //   262,144

  k_prep_all<<<10368, 256, 0, stream>>>(x, xt, xt_bf, Wq, Wkv, Wout, Wff1, Wff2,
                                        WqkvT, WoutT, Wff1T, Wff2T);
  k_gemm_bf<<<dim3(24, 64, 1), 256, 0, stream>>>(xt_bf, WqkvT, nullptr, qkv, 4096, 1536, 256, 256);
  k_prep_qk<<<2048, 256, 0, stream>>>(qkv, qfrag, kfrag);
  k_prep_vfrag<<<dim3(8, 16), 256, 0, stream>>>(qkv, vfrag);
  k_attn_den5<<<dim3(16, 4, 16), 256, 0, stream>>>(qfrag, kfrag, rdg);
  k_attn_out6<<<dim3(8, 8, 16), 256, 0, stream>>>(qfrag, kfrag, vfrag, rdg, ao_bf);
  k_gemm_bf<<<dim3(32, 8, 4), 256, 0, stream>>>(ao_bf, WoutT, bout, part, 512, 2048, 4096, 1024);
  k_ln<<<4096, 256, 0, stream>>>(xt, part, 4, g1, be1, y, y_bf);
  k_ff1g<<<dim3(16, 64), 256, 0, stream>>>(y_bf, Wff1T, bff1, gg_bf);
  k_gemm_bf<<<dim3(4, 64, 4), 256, 0, stream>>>(gg_bf, Wff2T, bff2, part, 4096, 256, 1024, 256);
  k_ln<<<4096, 256, 0, stream>>>(y, part, 4, g2, be2, out, nullptr);
}

// Round 10
// 217.878 us; speedup vs baseline: 2.0876x; 1.0596x over previous
//
#include <hip/hip_runtime.h>
#include <math.h>

#define KS_ 0.1803368801111244f   // 0.125 * log2(e)

typedef __attribute__((ext_vector_type(8))) short bf16x8;
typedef __attribute__((ext_vector_type(4))) short bf16x4;
typedef __attribute__((ext_vector_type(4))) float f32x4;

__device__ inline short f2bf(float f) {
  unsigned u = __builtin_bit_cast(unsigned, f);
  u += 0x7fff + ((u >> 16) & 1);
  return (short)(u >> 16);
}

// ---------- helper: 32x32 transpose tile of W [K][N] -> WT bf16 [N][K] ----------
__device__ inline void wt_tile(const float* __restrict__ W, short* __restrict__ WT,
                               int K, int N, int bx, int by, int t, float (*tile)[33]) {
  int n0 = bx * 32, k0 = by * 32;
  int tx = t & 31, ty = t >> 5;
#pragma unroll
  for (int r = 0; r < 32; r += 8)
    tile[ty + r][tx] = W[(size_t)(k0 + ty + r) * N + n0 + tx];
  __syncthreads();
#pragma unroll
  for (int r = 0; r < 32; r += 8)
    WT[(size_t)(n0 + ty + r) * K + k0 + tx] = f2bf(tile[tx][ty + r]);
}

// ---------- mega prep: x-transpose + all 5 weight transposes in one launch ----------
__global__ __launch_bounds__(256) void k_prep_all(const float* __restrict__ x, float* __restrict__ xt,
                                                  short* __restrict__ xtbf,
                                                  const float* __restrict__ Wq, const float* __restrict__ Wkv,
                                                  const float* __restrict__ Wout, const float* __restrict__ Wff1,
                                                  const float* __restrict__ Wff2,
                                                  short* __restrict__ WqkvT, short* __restrict__ WoutT,
                                                  short* __restrict__ Wff1T, short* __restrict__ Wff2T) {
  __shared__ float tile[32][33];
  int bid = blockIdx.x, t = threadIdx.x;
  if (bid < 8192) {
    wt_tile(Wout, WoutT, 4096, 2048, bid & 63, bid >> 6, t, tile);
  } else if (bid < 9216) {
    int r = bid - 8192;
    int bx = r & 7, by = (r >> 3) & 7, bm = r >> 6;
    int b = bm >> 3, m = bm & 7;
    int d0 = bx * 32, n0 = by * 32;
    int tx = t & 31, ty = t >> 5;
#pragma unroll
    for (int rr = 0; rr < 32; rr += 8) {
      int d = d0 + ty + rr, n = n0 + tx;
      tile[ty + rr][tx] = x[((size_t)(b * 256 + d) * 8 + m) * 256 + n];
    }
    __syncthreads();
#pragma unroll
    for (int rr = 0; rr < 32; rr += 8) {
      int n = n0 + ty + rr, d = d0 + tx;
      float v = tile[tx][ty + rr];
      size_t idx = ((size_t)(b * 256 + n) * 8 + m) * 256 + d;
      xt[idx] = v;
      xtbf[idx] = f2bf(v);
    }
  } else if (bid < 9344) {
    int r = bid - 9216;
    wt_tile(Wq, WqkvT, 256, 512, r & 15, r >> 4, t, tile);
  } else if (bid < 9600) {
    int r = bid - 9344;
    wt_tile(Wkv, WqkvT + 131072, 256, 1024, r & 31, r >> 5, t, tile);
  } else if (bid < 10112) {
    int r = bid - 9600;
    wt_tile(Wff1, Wff1T, 256, 2048, r & 63, r >> 6, t, tile);
  } else {
    int r = bid - 10112;
    wt_tile(Wff2, Wff2T, 1024, 256, r & 7, r >> 3, t, tile);
  }
}

// ---------- fused qkv GEMM with fragment-layout epilogue ----------
// A = xt_bf [4096][256]; Bt = WqkvT [1536][256]. grid (24, 64).
// bx: 0-7 -> q head h, 8-15 -> k head h, 16-23 -> v head h. Writes qfrag/kfrag/vfrag directly.
__global__ __launch_bounds__(256) void k_gemm_qkv(const short* __restrict__ A, const short* __restrict__ Bt,
                                                  short* __restrict__ qfrag, short* __restrict__ kfrag,
                                                  short* __restrict__ vfrag) {
  __shared__ short As[64 * 40];
  __shared__ short Bs[64 * 40];
  __shared__ short Cs[64 * 72];
  int t = threadIdx.x;
  int bx = blockIdx.x, by = blockIdx.y;
  int sel = bx >> 3, h = bx & 7;
  int row0 = by * 64, col0 = bx * 64;
  int b = by >> 5, n0 = (by * 8) & 255;
  int bh = b * 8 + h;
  int w = t >> 6, lane = t & 63, quad = lane >> 4, l16 = lane & 15;
  int wr = w >> 1, wc = w & 1;
  int lrow = t >> 2, lch = (t & 3) * 8;
  const short* Ap = A + (size_t)(row0 + lrow) * 256 + lch;
  const short* Bp = Bt + (size_t)(col0 + lrow) * 256 + lch;
  f32x4 acc[2][2] = {{{0,0,0,0},{0,0,0,0}},{{0,0,0,0},{0,0,0,0}}};
  bf16x8 av = *(const bf16x8*)(Ap);
  bf16x8 bv = *(const bf16x8*)(Bp);
  for (int k0 = 0; k0 < 256; k0 += 32) {
    *(bf16x8*)&As[lrow * 40 + lch] = av;
    *(bf16x8*)&Bs[lrow * 40 + lch] = bv;
    __syncthreads();
    if (k0 + 32 < 256) {
      av = *(const bf16x8*)(Ap + k0 + 32);
      bv = *(const bf16x8*)(Bp + k0 + 32);
    }
    bf16x8 af[2], bf[2];
#pragma unroll
    for (int rf = 0; rf < 2; rf++) af[rf] = *(const bf16x8*)&As[(wr * 32 + rf * 16 + l16) * 40 + quad * 8];
#pragma unroll
    for (int cf = 0; cf < 2; cf++) bf[cf] = *(const bf16x8*)&Bs[(wc * 32 + cf * 16 + l16) * 40 + quad * 8];
#pragma unroll
    for (int rf = 0; rf < 2; rf++)
#pragma unroll
      for (int cf = 0; cf < 2; cf++)
        acc[rf][cf] = __builtin_amdgcn_mfma_f32_16x16x32_bf16(af[rf], bf[cf], acc[rf][cf], 0, 0, 0);
    __syncthreads();
  }
  // ---- stage result tile to LDS as bf16 ----
  if (sel < 2) {
    // row-major Cs[row][d], stride 72 (16B-aligned chunks for b128 reads)
#pragma unroll
    for (int rf = 0; rf < 2; rf++)
#pragma unroll
      for (int cf = 0; cf < 2; cf++) {
        int col = wc * 32 + cf * 16 + l16;
#pragma unroll
        for (int r = 0; r < 4; r++)
          Cs[(wr * 32 + rf * 16 + quad * 4 + r) * 72 + col] = f2bf(acc[rf][cf][r]);
      }
  } else {
    // transposed CsT[d][row], stride 72; 4 consecutive rows -> one 8B store
#pragma unroll
    for (int rf = 0; rf < 2; rf++)
#pragma unroll
      for (int cf = 0; cf < 2; cf++) {
        int col = wc * 32 + cf * 16 + l16;
        bf16x4 pk;
#pragma unroll
        for (int r = 0; r < 4; r++) pk[r] = f2bf(acc[rf][cf][r]);
        *(bf16x4*)&Cs[col * 72 + wr * 32 + rf * 16 + quad * 4] = pk;
      }
  }
  __syncthreads();
  // ---- fragment-order global writes ----
  if (sel < 2) {
    short* dst = sel ? kfrag : qfrag;
    int it = n0 >> 4, l16b = n0 & 8;
#pragma unroll
    for (int cidx = 0; cidx < 2; cidx++) {
      int chunk = t + cidx * 256;        // bits: m[8:6] ks[5] q2[4:3] n[2:0]
      int m = chunk >> 6, ks2 = (chunk >> 5) & 1, q2 = (chunk >> 3) & 3, n = chunk & 7;
      bf16x8 val = *(const bf16x8*)&Cs[(n * 8 + m) * 72 + ks2 * 32 + q2 * 8];
      size_t off = ((size_t)(bh * 128 + m * 16 + it) * 2 + ks2) * 512 + (q2 * 16 + l16b + n) * 8;
      *(bf16x8*)(dst + off) = val;
    }
  } else {
    int jc = n0 >> 5, jf = (n0 >> 4) & 1, qbase = (n0 & 8) >> 2;   // quad base 0 or 2
#pragma unroll
    for (int cidx = 0; cidx < 2; cidx++) {
      int chunk = t + cidx * 256;        // bits: qd[8] m0[7:6] dt[5:4] l16[3:0]
      int qd = chunk >> 8, m0 = (chunk >> 6) & 3, dtt = (chunk >> 4) & 3, l16c = chunk & 15;
      int d = dtt * 16 + l16c;
      unsigned u[4];
#pragma unroll
      for (int e3 = 0; e3 < 4; e3++)
        u[e3] = *(const unsigned*)&Cs[d * 72 + qd * 32 + e3 * 8 + 2 * m0];
      uint4 pv;
      pv.x = __builtin_amdgcn_perm(u[1], u[0], 0x05040100u);
      pv.y = __builtin_amdgcn_perm(u[3], u[2], 0x05040100u);
      pv.z = __builtin_amdgcn_perm(u[1], u[0], 0x07060302u);
      pv.w = __builtin_amdgcn_perm(u[3], u[2], 0x07060302u);
      int quad2 = qbase + qd;
      size_t cid = (((size_t)(bh * 8 + jc) * 4 + m0) * 4 + dtt) * 2 + jf;
      *(bf16x8*)(vfrag + cid * 512 + (quad2 * 16 + l16c) * 8) = __builtin_bit_cast(bf16x8, pv);
    }
  }
}

// ---------- bf16 MFMA GEMM with split-K + register-prefetch pipeline ----------
__global__ __launch_bounds__(256) void k_gemm_bf(const short* __restrict__ A, const short* __restrict__ Bt,
                                                 const float* __restrict__ bias, float* __restrict__ C,
                                                 int M, int N, int K, int Ks) {
  __shared__ short As[64 * 40];
  __shared__ short Bs[64 * 40];
  int t = threadIdx.x;
  int row0 = blockIdx.y * 64, col0 = blockIdx.x * 64;
  int kp = blockIdx.z;
  int kbeg = kp * Ks, kend = kbeg + Ks;
  int w = t >> 6, lane = t & 63, quad = lane >> 4, l16 = lane & 15;
  int wr = w >> 1, wc = w & 1;
  int lrow = t >> 2, lch = (t & 3) * 8;
  const short* Ap = A + (size_t)(row0 + lrow) * K + lch;
  const short* Bp = Bt + (size_t)(col0 + lrow) * K + lch;
  f32x4 acc[2][2] = {{{0,0,0,0},{0,0,0,0}},{{0,0,0,0},{0,0,0,0}}};
  bf16x8 av = *(const bf16x8*)(Ap + kbeg);
  bf16x8 bv = *(const bf16x8*)(Bp + kbeg);
  for (int k0 = kbeg; k0 < kend; k0 += 32) {
    *(bf16x8*)&As[lrow * 40 + lch] = av;
    *(bf16x8*)&Bs[lrow * 40 + lch] = bv;
    __syncthreads();
    if (k0 + 32 < kend) {
      av = *(const bf16x8*)(Ap + k0 + 32);
      bv = *(const bf16x8*)(Bp + k0 + 32);
    }
    bf16x8 af[2], bf[2];
#pragma unroll
    for (int rf = 0; rf < 2; rf++) af[rf] = *(const bf16x8*)&As[(wr * 32 + rf * 16 + l16) * 40 + quad * 8];
#pragma unroll
    for (int cf = 0; cf < 2; cf++) bf[cf] = *(const bf16x8*)&Bs[(wc * 32 + cf * 16 + l16) * 40 + quad * 8];
#pragma unroll
    for (int rf = 0; rf < 2; rf++)
#pragma unroll
      for (int cf = 0; cf < 2; cf++)
        acc[rf][cf] = __builtin_amdgcn_mfma_f32_16x16x32_bf16(af[rf], bf[cf], acc[rf][cf], 0, 0, 0);
    __syncthreads();
  }
  float* Cp = C + (size_t)kp * M * N;
#pragma unroll
  for (int rf = 0; rf < 2; rf++)
#pragma unroll
    for (int cf = 0; cf < 2; cf++) {
      int col = col0 + wc * 32 + cf * 16 + l16;
      float vb = (bias && kp == 0) ? bias[col] : 0.0f;
#pragma unroll
      for (int r = 0; r < 4; r++) {
        int row = row0 + wr * 32 + rf * 16 + quad * 4 + r;
        Cp[(size_t)row * N + col] = acc[rf][cf][r] + vb;
      }
    }
}

// ---------- fused ff1 GEMM + GEGLU ----------
__global__ __launch_bounds__(256) void k_ff1g(const short* __restrict__ A, const short* __restrict__ Bt,
                                              const float* __restrict__ bias, short* __restrict__ gg) {
  __shared__ short As[64 * 40];
  __shared__ short Ba[64 * 40];
  __shared__ short Bg[64 * 40];
  int t = threadIdx.x;
  int colA0 = blockIdx.x * 64, row0 = blockIdx.y * 64;
  int w = t >> 6, lane = t & 63, quad = lane >> 4, l16 = lane & 15;
  int wr = w >> 1, wc = w & 1;
  int lrow = t >> 2, lch = (t & 3) * 8;
  const short* Ap  = A + (size_t)(row0 + lrow) * 256 + lch;
  const short* Bpa = Bt + (size_t)(colA0 + lrow) * 256 + lch;
  const short* Bpg = Bt + (size_t)(1024 + colA0 + lrow) * 256 + lch;
  f32x4 za = {0, 0, 0, 0};
  f32x4 acc_a[2][2] = {{za, za}, {za, za}};
  f32x4 acc_g[2][2] = {{za, za}, {za, za}};
  bf16x8 av = *(const bf16x8*)(Ap);
  bf16x8 bva = *(const bf16x8*)(Bpa);
  bf16x8 bvg = *(const bf16x8*)(Bpg);
  for (int k0 = 0; k0 < 256; k0 += 32) {
    *(bf16x8*)&As[lrow * 40 + lch] = av;
    *(bf16x8*)&Ba[lrow * 40 + lch] = bva;
    *(bf16x8*)&Bg[lrow * 40 + lch] = bvg;
    __syncthreads();
    if (k0 + 32 < 256) {
      av  = *(const bf16x8*)(Ap + k0 + 32);
      bva = *(const bf16x8*)(Bpa + k0 + 32);
      bvg = *(const bf16x8*)(Bpg + k0 + 32);
    }
    bf16x8 af[2], ba[2], bg[2];
#pragma unroll
    for (int rf = 0; rf < 2; rf++) af[rf] = *(const bf16x8*)&As[(wr * 32 + rf * 16 + l16) * 40 + quad * 8];
#pragma unroll
    for (int cf = 0; cf < 2; cf++) {
      ba[cf] = *(const bf16x8*)&Ba[(wc * 32 + cf * 16 + l16) * 40 + quad * 8];
      bg[cf] = *(const bf16x8*)&Bg[(wc * 32 + cf * 16 + l16) * 40 + quad * 8];
    }
#pragma unroll
    for (int rf = 0; rf < 2; rf++)
#pragma unroll
      for (int cf = 0; cf < 2; cf++) {
        acc_a[rf][cf] = __builtin_amdgcn_mfma_f32_16x16x32_bf16(af[rf], ba[cf], acc_a[rf][cf], 0, 0, 0);
        acc_g[rf][cf] = __builtin_amdgcn_mfma_f32_16x16x32_bf16(af[rf], bg[cf], acc_g[rf][cf], 0, 0, 0);
      }
    __syncthreads();
  }
#pragma unroll
  for (int rf = 0; rf < 2; rf++)
#pragma unroll
    for (int cf = 0; cf < 2; cf++) {
      int col = colA0 + wc * 32 + cf * 16 + l16;
      float ba_ = bias[col], bg_ = bias[1024 + col];
#pragma unroll
      for (int r = 0; r < 4; r++) {
        int row = row0 + wr * 32 + rf * 16 + quad * 4 + r;
        float a = acc_a[rf][cf][r] + ba_;
        float g = acc_g[rf][cf][r] + bg_;
        float ge = 0.5f * g * (1.0f + erff(g * 0.70710678118654752f));
        gg[(size_t)row * 1024 + col] = f2bf(a * ge);
      }
    }
}

// ---------- attention pass 1: 2 K-frags per wave; grid (ct2 16, mp 4, bh 16) ----------
__global__ __launch_bounds__(256) void k_attn_den5(const short* __restrict__ qfrag, const short* __restrict__ kfrag,
                                                   float* __restrict__ rdg) {
  int ct2 = blockIdx.x, mp = blockIdx.y, bh = blockIdx.z;
  int t = threadIdx.x;
  int w = t >> 6, lane = t & 63;
  int rt0 = ct2 * 8 + w * 2;
  bf16x8 bfr[2][2];
#pragma unroll
  for (int cf = 0; cf < 2; cf++)
#pragma unroll
    for (int ks = 0; ks < 2; ks++)
      bfr[cf][ks] = *(const bf16x8*)(kfrag + ((size_t)((bh * 128 + rt0 + cf) * 2 + ks)) * 512 + lane * 8);
  for (int mi = 0; mi < 2; mi++) {
    int m = mp * 2 + mi;
    float fa0 = 0.0f, fa1 = 0.0f;
#pragma unroll 4
    for (int it2 = 0; it2 < 16; it2++) {
      const short* ap = qfrag + ((size_t)((bh * 128 + m * 16 + it2) * 2)) * 512 + lane * 8;
      bf16x8 a0 = *(const bf16x8*)ap;
      bf16x8 a1 = *(const bf16x8*)(ap + 512);
      f32x4 c0 = {0, 0, 0, 0}, c1 = {0, 0, 0, 0};
      c0 = __builtin_amdgcn_mfma_f32_16x16x32_bf16(a0, bfr[0][0], c0, 0, 0, 0);
      c0 = __builtin_amdgcn_mfma_f32_16x16x32_bf16(a1, bfr[0][1], c0, 0, 0, 0);
      c1 = __builtin_amdgcn_mfma_f32_16x16x32_bf16(a0, bfr[1][0], c1, 0, 0, 0);
      c1 = __builtin_amdgcn_mfma_f32_16x16x32_bf16(a1, bfr[1][1], c1, 0, 0, 0);
#pragma unroll
      for (int r = 0; r < 4; r++) {
        fa0 += __builtin_amdgcn_exp2f(c0[r] * KS_);
        fa1 += __builtin_amdgcn_exp2f(c1[r] * KS_);
      }
    }
    fa0 += __shfl_xor(fa0, 16); fa0 += __shfl_xor(fa0, 32);
    fa1 += __shfl_xor(fa1, 16); fa1 += __shfl_xor(fa1, 32);
    if (lane < 16) {
      rdg[(size_t)(bh * 8 + m) * 2048 + rt0 * 16 + lane] = -__builtin_amdgcn_logf(fa0);
      rdg[(size_t)(bh * 8 + m) * 2048 + (rt0 + 1) * 16 + lane] = -__builtin_amdgcn_logf(fa1);
    }
  }
}

// ---------- attention pass 2: 2 i-tiles/block + next-jc register prefetch; grid (z 8, itp 8, bh 16) ----------
__global__ __launch_bounds__(256) void k_attn_out6(const short* __restrict__ qfrag, const short* __restrict__ kfrag,
                                                   const short* __restrict__ vfrag, const float* __restrict__ rdg,
                                                   short* __restrict__ ao) {
  __shared__ float red[4 * 64 * 17];
  int z = blockIdx.x, itp = blockIdx.y, bh = blockIdx.z;
  int b = bh >> 3, h = bh & 7;
  int t = threadIdx.x, w = t >> 6, lane = t & 63, quad = lane >> 4, l16 = lane & 15;
  const float* rb = rdg + (size_t)bh * 16384;
  f32x4 z4 = {0, 0, 0, 0};
  bf16x8 qf[2][2][2];
#pragma unroll
  for (int iti = 0; iti < 2; iti++)
#pragma unroll
    for (int mm = 0; mm < 2; mm++)
#pragma unroll
      for (int ks = 0; ks < 2; ks++)
        qf[iti][mm][ks] = *(const bf16x8*)(qfrag +
            ((size_t)((bh * 128 + (2 * w + mm) * 16 + itp * 2 + iti) * 2 + ks)) * 512 + lane * 8);
  f32x4 acc[2][4];
#pragma unroll
  for (int iti = 0; iti < 2; iti++)
#pragma unroll
    for (int dt = 0; dt < 4; dt++) acc[iti][dt] = z4;
  bf16x8 vf[4][2], kf[2][2];
  float4 nv0[2], nv1[2];
#pragma unroll
  for (int dt = 0; dt < 4; dt++)
#pragma unroll
    for (int jf = 0; jf < 2; jf++)
      vf[dt][jf] = *(const bf16x8*)(vfrag + ((((size_t)(bh * 8 + 0) * 4 + w) * 4 + dt) * 2 + jf) * 512 + lane * 8);
#pragma unroll
  for (int jf = 0; jf < 2; jf++) {
    const short* kp = kfrag + ((size_t)((bh * 128 + z * 16 + 0 * 2 + jf) * 2)) * 512 + lane * 8;
    kf[jf][0] = *(const bf16x8*)kp;
    kf[jf][1] = *(const bf16x8*)(kp + 512);
    nv0[jf] = *(const float4*)(rb + (size_t)(2 * w) * 2048 + z * 256 + 0 * 32 + jf * 16 + quad * 4);
    nv1[jf] = *(const float4*)(rb + (size_t)(2 * w + 1) * 2048 + z * 256 + 0 * 32 + jf * 16 + quad * 4);
  }
  for (int jc = 0; jc < 8; jc++) {
    bf16x8 vfn[4][2], kfn[2][2];
    float4 nv0n[2], nv1n[2];
    if (jc < 7) {
      int jn = jc + 1;
#pragma unroll
      for (int dt = 0; dt < 4; dt++)
#pragma unroll
        for (int jf = 0; jf < 2; jf++)
          vfn[dt][jf] = *(const bf16x8*)(vfrag + ((((size_t)(bh * 8 + jn) * 4 + w) * 4 + dt) * 2 + jf) * 512 + lane * 8);
#pragma unroll
      for (int jf = 0; jf < 2; jf++) {
        const short* kp = kfrag + ((size_t)((bh * 128 + z * 16 + jn * 2 + jf) * 2)) * 512 + lane * 8;
        kfn[jf][0] = *(const bf16x8*)kp;
        kfn[jf][1] = *(const bf16x8*)(kp + 512);
        nv0n[jf] = *(const float4*)(rb + (size_t)(2 * w) * 2048 + z * 256 + jn * 32 + jf * 16 + quad * 4);
        nv1n[jf] = *(const float4*)(rb + (size_t)(2 * w + 1) * 2048 + z * 256 + jn * 32 + jf * 16 + quad * 4);
      }
    }
    float n0[2][4] = {{nv0[0].x, nv0[0].y, nv0[0].z, nv0[0].w}, {nv0[1].x, nv0[1].y, nv0[1].z, nv0[1].w}};
    float n1[2][4] = {{nv1[0].x, nv1[0].y, nv1[0].z, nv1[0].w}, {nv1[1].x, nv1[1].y, nv1[1].z, nv1[1].w}};
#pragma unroll
    for (int iti = 0; iti < 2; iti++) {
      f32x4 c[2][2] = {{z4, z4}, {z4, z4}};
#pragma unroll
      for (int jf = 0; jf < 2; jf++)
#pragma unroll
        for (int mm = 0; mm < 2; mm++) {
          c[jf][mm] = __builtin_amdgcn_mfma_f32_16x16x32_bf16(kf[jf][0], qf[iti][mm][0], c[jf][mm], 0, 0, 0);
          c[jf][mm] = __builtin_amdgcn_mfma_f32_16x16x32_bf16(kf[jf][1], qf[iti][mm][1], c[jf][mm], 0, 0, 0);
        }
      bf16x8 pf[2];
#pragma unroll
      for (int jf = 0; jf < 2; jf++) {
        unsigned u[8];
#pragma unroll
        for (int e = 0; e < 4; e++) {
          u[e]     = __builtin_bit_cast(unsigned, __builtin_amdgcn_exp2f(fmaf(c[jf][0][e], KS_, n0[jf][e]))) + 0x8000u;
          u[e + 4] = __builtin_bit_cast(unsigned, __builtin_amdgcn_exp2f(fmaf(c[jf][1][e], KS_, n1[jf][e]))) + 0x8000u;
        }
        uint4 pv;
        pv.x = __builtin_amdgcn_perm(u[1], u[0], 0x07060302u);
        pv.y = __builtin_amdgcn_perm(u[3], u[2], 0x07060302u);
        pv.z = __builtin_amdgcn_perm(u[5], u[4], 0x07060302u);
        pv.w = __builtin_amdgcn_perm(u[7], u[6], 0x07060302u);
        pf[jf] = __builtin_bit_cast(bf16x8, pv);
      }
#pragma unroll
      for (int dt = 0; dt < 4; dt++)
#pragma unroll
        for (int jf = 0; jf < 2; jf++)
          acc[iti][dt] = __builtin_amdgcn_mfma_f32_16x16x32_bf16(vf[dt][jf], pf[jf], acc[iti][dt], 0, 0, 0);
    }
    if (jc < 7) {
#pragma unroll
      for (int dt = 0; dt < 4; dt++)
#pragma unroll
        for (int jf = 0; jf < 2; jf++) vf[dt][jf] = vfn[dt][jf];
#pragma unroll
      for (int jf = 0; jf < 2; jf++) {
        kf[jf][0] = kfn[jf][0]; kf[jf][1] = kfn[jf][1];
        nv0[jf] = nv0n[jf]; nv1[jf] = nv1n[jf];
      }
    }
  }
  for (int iti = 0; iti < 2; iti++) {
#pragma unroll
    for (int dt = 0; dt < 4; dt++)
#pragma unroll
      for (int r = 0; r < 4; r++)
        red[w * 1088 + (dt * 16 + quad * 4 + r) * 17 + l16] = acc[iti][dt][r];
    __syncthreads();
    {
      int i = t >> 4, dg = t & 15;
      float s[4] = {0, 0, 0, 0};
#pragma unroll
      for (int w2 = 0; w2 < 4; w2++)
#pragma unroll
        for (int r2 = 0; r2 < 4; r2++)
          s[r2] += red[w2 * 1088 + (dg * 4 + r2) * 17 + i];
      bf16x4 ov;
#pragma unroll
      for (int r2 = 0; r2 < 4; r2++) ov[r2] = f2bf(s[r2]);
      *(bf16x4*)(ao + (size_t)((b * 256 + itp * 32 + iti * 16 + i) * 8 + z) * 512 + h * 64 + dg * 4) = ov;
    }
    __syncthreads();
  }
}

// ---------- fused residual(np split-K partials) + layernorm; optional bf16 copy ----------
__global__ __launch_bounds__(256) void k_ln(const float* __restrict__ X, const float* __restrict__ P, int np,
                                            const float* __restrict__ g, const float* __restrict__ be,
                                            float* __restrict__ Y, short* __restrict__ Ybf) {
  __shared__ float sm[8];
  int row = blockIdx.x, t = threadIdx.x;
  int lane = t & 63, w = t >> 6;
  size_t base = (size_t)row * 256;
  float v = X[base + t];
  for (int p = 0; p < np; p++) v += P[(size_t)p * 1048576 + base + t];
  float s = v;
  s += __shfl_xor(s, 1); s += __shfl_xor(s, 2); s += __shfl_xor(s, 4);
  s += __shfl_xor(s, 8); s += __shfl_xor(s, 16); s += __shfl_xor(s, 32);
  if (lane == 0) sm[w] = s;
  __syncthreads();
  float mu = (sm[0] + sm[1] + sm[2] + sm[3]) * (1.0f / 256.0f);
  float dv = v - mu;
  float s2 = dv * dv;
  s2 += __shfl_xor(s2, 1); s2 += __shfl_xor(s2, 2); s2 += __shfl_xor(s2, 4);
  s2 += __shfl_xor(s2, 8); s2 += __shfl_xor(s2, 16); s2 += __shfl_xor(s2, 32);
  if (lane == 0) sm[4 + w] = s2;
  __syncthreads();
  float var = (sm[4] + sm[5] + sm[6] + sm[7]) * (1.0f / 256.0f);
  float rs = rsqrtf(var + 1e-5f);
  float res = dv * rs * g[t] + be[t];
  Y[base + t] = res;
  if (Ybf) Ybf[base + t] = f2bf(res);
}

extern "C" void kernel_launch(void* const* d_in, const int* in_sizes, int n_in,
                              void* d_out, int out_size, void* d_ws, size_t ws_size,
                              hipStream_t stream) {
  const float* x    = (const float*)d_in[0];
  const float* Wq   = (const float*)d_in[1];
  const float* Wkv  = (const float*)d_in[2];
  const float* Wout = (const float*)d_in[3];
  const float* bout = (const float*)d_in[4];
  const float* g1   = (const float*)d_in[5];
  const float* be1  = (const float*)d_in[6];
  const float* Wff1 = (const float*)d_in[7];
  const float* bff1 = (const float*)d_in[8];
  const float* Wff2 = (const float*)d_in[9];
  const float* bff2 = (const float*)d_in[10];
  const float* g2   = (const float*)d_in[11];
  const float* be2  = (const float*)d_in[12];
  float* out = (float*)d_out;
  float* w = (float*)d_ws;

  // fp32 zone
  float* xt   = w;              // 1,048,576
  float* part = w + 1048576;    // split-K partials (4 x 1M, two phases)
  float* y    = w + 9437184;    // 1,048,576
  float* rdg  = w + 11534336;   //   262,144  -log2(den), [bh*8+m][2048]
  // bf16 zone
  short* sb     = (short*)(w + 11796480);
  short* qfrag  = sb;                    // 2,097,152
  short* kfrag  = sb + 2097152;          // 2,097,152
  short* vfrag  = sb + 4194304;          // 2,097,152
  short* xt_bf  = sb + 6291456;          // 1,048,576
  short* ao_bf  = sb + 7340032;          // 2,097,152
  short* y_bf   = sb + 9437184;          // 1,048,576
  short* gg_bf  = sb + 10485760;         // 4,194,304
  short* WqkvT  = sb + 14680064;         //   393,216  [1536][256]
  short* WoutT  = sb + 15073280;         // 8,388,608
  short* Wff1T  = sb + 23461888;         //   524,288
  short* Wff2T  = sb + 23986176;         //   262,144

  k_prep_all<<<10368, 256, 0, stream>>>(x, xt, xt_bf, Wq, Wkv, Wout, Wff1, Wff2,
                                        WqkvT, WoutT, Wff1T, Wff2T);
  k_gemm_qkv<<<dim3(24, 64), 256, 0, stream>>>(xt_bf, WqkvT, qfrag, kfrag, vfrag);
  k_attn_den5<<<dim3(16, 4, 16), 256, 0, stream>>>(qfrag, kfrag, rdg);
  k_attn_out6<<<dim3(8, 8, 16), 256, 0, stream>>>(qfrag, kfrag, vfrag, rdg, ao_bf);
  k_gemm_bf<<<dim3(32, 8, 4), 256, 0, stream>>>(ao_bf, WoutT, bout, part, 512, 2048, 4096, 1024);
  k_ln<<<4096, 256, 0, stream>>>(xt, part, 4, g1, be1, y, y_bf);
  k_ff1g<<<dim3(16, 64), 256, 0, stream>>>(y_bf, Wff1T, bff1, gg_bf);
  k_gemm_bf<<<dim3(4, 64, 4), 256, 0, stream>>>(gg_bf, Wff2T, bff2, part, 4096, 256, 1024, 256);
  k_ln<<<4096, 256, 0, stream>>>(y, part, 4, g2, be2, out, nullptr);
}